// Round 20
// baseline (292.717 us; speedup 1.0000x reference)
//
#include <hip/hip_runtime.h>
#include <math.h>

// ---------------------------------------------------------------------------
// ConformerBlock MFMA implementation.
// B=4, T=2048, D=512, H=8, hd=64, K=31.  M = B*T = 8192.
// Bitlinear GEMMs + in_proj: int8 MFMA (BK=128, XCD-swizzled). bf16 residual
// stream. Attention: swapped-operand 32x32 MFMA, LDS-staged K/V (dbuf),
// max-free softmax, k-split x1, bh-affinity XCD remap. in_proj scatters
// packed kvqp; FFN-up applies snake in epilogue. Wave-per-row norms/quant.
// ---------------------------------------------------------------------------

typedef int   v4i __attribute__((ext_vector_type(4)));
typedef float v4f __attribute__((ext_vector_type(4)));
typedef float v16f __attribute__((ext_vector_type(16)));
typedef short v8s __attribute__((ext_vector_type(8)));
typedef unsigned short u16;

#define GLOAD_LDS(g, l) __builtin_amdgcn_global_load_lds( \
    (const __attribute__((address_space(1))) void*)(g),   \
    (__attribute__((address_space(3))) void*)(l), 16, 0, 0)

__device__ __forceinline__ float blk_sum256(float v, float* sm) {
#pragma unroll
  for (int m = 32; m; m >>= 1) v += __shfl_xor(v, m);
  int w = threadIdx.x >> 6;
  __syncthreads();
  if ((threadIdx.x & 63) == 0) sm[w] = v;
  __syncthreads();
  return sm[0] + sm[1] + sm[2] + sm[3];
}

__device__ __forceinline__ float blk_max256(float v, float* sm) {
#pragma unroll
  for (int m = 32; m; m >>= 1) v = fmaxf(v, __shfl_xor(v, m));
  int w = threadIdx.x >> 6;
  __syncthreads();
  if ((threadIdx.x & 63) == 0) sm[w] = v;
  __syncthreads();
  return fmaxf(fmaxf(sm[0], sm[1]), fmaxf(sm[2], sm[3]));
}

__device__ __forceinline__ u16 f2bf(float f) {
  union { float f; unsigned u; } x;
  x.f = f;
  unsigned r = x.u + 0x7fffu + ((x.u >> 16) & 1u);
  return (u16)(r >> 16);
}

__device__ __forceinline__ float bf2f(u16 u) {
  union { unsigned u; float f; } x;
  x.u = ((unsigned)u) << 16;
  return x.f;
}

// XCD-aware bijective block remap (nwg divisible by 8 for all our grids).
__device__ __forceinline__ void xcd_tiles(int& tx, int& ty) {
  int nx = gridDim.x;
  int flat = blockIdx.y * nx + blockIdx.x;
  int nwg = nx * gridDim.y;
  int cpx = nwg >> 3;
  int swz = (flat & 7) * cpx + (flat >> 3);
  ty = swz / nx;
  tx = swz - ty * nx;
}

// ---------------------------------------------------------------------------
// Weight reductions: widx 0..5 ternary (sum|w| -> mean), widx 6 in_proj
// (max|w| for int8 quant). grid = 7*64.
// ---------------------------------------------------------------------------
__global__ __launch_bounds__(256) void wabs_stage1(
    const float* __restrict__ w0, const float* __restrict__ w1,
    const float* __restrict__ w2, const float* __restrict__ w3,
    const float* __restrict__ w4, const float* __restrict__ w5,
    const float* __restrict__ w6, float* __restrict__ part) {
  __shared__ float sm[4];
  const float* ws[7] = {w0, w1, w2, w3, w4, w5, w6};
  const int ns[7] = {1048576, 1048576, 524288, 262144, 1048576, 1048576, 786432};
  int widx = blockIdx.x >> 6;
  int chunk = blockIdx.x & 63;
  const float* w = ws[widx];
  int n = ns[widx];
  if (widx < 6) {
    float s = 0.f;
    for (int i = chunk * 256 + threadIdx.x; i < n; i += 64 * 256) s += fabsf(w[i]);
    s = blk_sum256(s, sm);
    if (threadIdx.x == 0) part[widx * 64 + chunk] = s;
  } else {
    float s = 0.f;
    for (int i = chunk * 256 + threadIdx.x; i < n; i += 64 * 256) s = fmaxf(s, fabsf(w[i]));
    s = blk_max256(s, sm);
    if (threadIdx.x == 0) part[widx * 64 + chunk] = s;
  }
}

// stage2 folded in: every block recomputes the 64-partial reduce for its widx.
// widx 0..5: ternary quant (clip +-1), scales = mean|w|.
// widx 6: int8 quant (clip +-127), scales = absmax/127.
__global__ __launch_bounds__(256) void wquant_all(
    const float* __restrict__ w0, const float* __restrict__ w1,
    const float* __restrict__ w2, const float* __restrict__ w3,
    const float* __restrict__ w4, const float* __restrict__ w5,
    const float* __restrict__ w6,
    const float* __restrict__ part, float* __restrict__ scales,
    signed char* __restrict__ out) {
  const float* ws[7] = {w0, w1, w2, w3, w4, w5, w6};
  const int ns[7] = {1048576, 1048576, 524288, 262144, 1048576, 1048576, 786432};
  const int offs[7] = {0, 1048576, 2097152, 2621440, 2883584, 3932160, 4980736};
  int widx = blockIdx.y;
  const float* w = ws[widx];
  int n = ns[widx];
  signed char* o = out + offs[widx];
  float s, clipv;
  if (widx < 6) {
    float ssum = 0.f;
#pragma unroll 8
    for (int i = 0; i < 64; ++i) ssum += part[widx * 64 + i];
    float wsc = fmaxf(ssum / (float)n, 1e-5f);
    if (blockIdx.x == 0 && threadIdx.x == 0) scales[widx] = wsc;
    s = 1.0f / wsc;
    clipv = 1.f;
  } else {
    float am = 0.f;
#pragma unroll 8
    for (int i = 0; i < 64; ++i) am = fmaxf(am, part[widx * 64 + i]);
    float step = fmaxf(am, 1e-5f) * (1.0f / 127.0f);
    if (blockIdx.x == 0 && threadIdx.x == 0) scales[widx] = step;
    s = 1.0f / step;
    clipv = 127.f;
  }
  for (int i = blockIdx.x * 256 + threadIdx.x; i < n; i += 128 * 256)
    o[i] = (signed char)(int)fminf(fmaxf(rintf(w[i] * s), -clipv), clipv);
}

// bf16 out_proj convert (x4 vectorized) + snake exp tables in one launch.
// grid = 256 (out_proj, 4 elems/thread) + 8 (tables) = 264
__global__ __launch_bounds__(256) void wcvt_tabs(
    const float* __restrict__ op, u16* __restrict__ wb,
    const float* __restrict__ a1, const float* __restrict__ b1,
    const float* __restrict__ a2, const float* __restrict__ b2,
    float* __restrict__ tabs) {
  int bid = blockIdx.x;
  if (bid < 256) {
    int i = bid * 256 + threadIdx.x;  // 0..65535, elem base = i*4
    float4 f = *(const float4*)(op + (size_t)i * 4);
    u16* dst = wb + (size_t)i * 4;
    dst[0] = f2bf(f.x); dst[1] = f2bf(f.y); dst[2] = f2bf(f.z); dst[3] = f2bf(f.w);
  } else {
    int i = (bid - 256) * 256 + threadIdx.x;
    if (i < 2048) {
      tabs[i] = __expf(a1[i]);
      tabs[2048 + i] = 1.0f / (__expf(b1[i]) + 1e-9f);
      tabs[4096 + i] = __expf(a2[i]);
      tabs[6144 + i] = 1.0f / (__expf(b2[i]) + 1e-9f);
    }
  }
}

// ---------------------------------------------------------------------------
// Wave-per-row RMSNorm over f32 rows of 512 (4 rows/block): emits bf16 copy
// of x AND int8 quant + dq.
// ---------------------------------------------------------------------------
__global__ __launch_bounds__(256) void rmsnorm_f32x(
    const float* __restrict__ x, const float* __restrict__ w,
    signed char* __restrict__ out8, u16* __restrict__ xbf,
    float* __restrict__ dq) {
  const int tid = threadIdx.x;
  const int lane = tid & 63, wv = tid >> 6;
  const int row = blockIdx.x * 4 + wv;
  const int c0 = lane * 8;
  const float* xr = x + (size_t)row * 512 + c0;
  float4 f0 = *(const float4*)xr;
  float4 f1 = *(const float4*)(xr + 4);
  float fin[8] = {f0.x, f0.y, f0.z, f0.w, f1.x, f1.y, f1.z, f1.w};
  v8s xb;
  float v[8];
  float ss = 0.f;
#pragma unroll
  for (int j = 0; j < 8; ++j) {
    u16 b = f2bf(fin[j]);
    xb[j] = (short)b;
    v[j] = bf2f(b);
    ss = fmaf(v[j], v[j], ss);
  }
  *(v8s*)(xbf + (size_t)row * 512 + c0) = xb;
#pragma unroll
  for (int m = 1; m < 64; m <<= 1) ss += __shfl_xor(ss, m);
  float sc = 1.0f / sqrtf(ss * (1.0f / 512.0f) + 1e-6f);
  float4 w0 = *(const float4*)(w + c0);
  float4 w1 = *(const float4*)(w + c0 + 4);
  float wv8[8] = {w0.x, w0.y, w0.z, w0.w, w1.x, w1.y, w1.z, w1.w};
  float y[8];
  float am = 0.f;
#pragma unroll
  for (int j = 0; j < 8; ++j) {
    y[j] = v[j] * sc * wv8[j];
    am = fmaxf(am, fabsf(y[j]));
  }
#pragma unroll
  for (int m = 1; m < 64; m <<= 1) am = fmaxf(am, __shfl_xor(am, m));
  float amc = fmaxf(am, 1e-5f);
  float s = 127.0f / amc;
  unsigned long long pkt = 0;
#pragma unroll
  for (int j = 0; j < 8; ++j) {
    int q = (int)rintf(y[j] * s);
    pkt |= ((unsigned long long)(unsigned char)(signed char)q) << (8 * j);
  }
  *(unsigned long long*)(out8 + (size_t)row * 512 + c0) = pkt;
  if (lane == 0) dq[row] = amc * (1.0f / 127.0f);
}

// ---------------------------------------------------------------------------
// Wave-per-row RMSNorm over bf16 rows of 512 (4 rows/block).
// mode 0: f32 out.  mode 1: int8-quant out + dq.  mode 2: bf16 out.
// ---------------------------------------------------------------------------
__global__ __launch_bounds__(256) void rmsnorm_wave(
    const u16* __restrict__ x, const float* __restrict__ w, int mode,
    float* __restrict__ outf, signed char* __restrict__ out8,
    u16* __restrict__ outb, float* __restrict__ dq) {
  const int tid = threadIdx.x;
  const int lane = tid & 63, wv = tid >> 6;
  const int row = blockIdx.x * 4 + wv;
  const int c0 = lane * 8;
  v8s xv = *(const v8s*)(x + (size_t)row * 512 + c0);
  float v[8];
  float ss = 0.f;
#pragma unroll
  for (int j = 0; j < 8; ++j) {
    v[j] = bf2f((u16)xv[j]);
    ss = fmaf(v[j], v[j], ss);
  }
#pragma unroll
  for (int m = 1; m < 64; m <<= 1) ss += __shfl_xor(ss, m);
  float sc = 1.0f / sqrtf(ss * (1.0f / 512.0f) + 1e-6f);
  float4 w0 = *(const float4*)(w + c0);
  float4 w1 = *(const float4*)(w + c0 + 4);
  float wv8[8] = {w0.x, w0.y, w0.z, w0.w, w1.x, w1.y, w1.z, w1.w};
  float y[8];
#pragma unroll
  for (int j = 0; j < 8; ++j) y[j] = v[j] * sc * wv8[j];
  if (mode == 0) {
    float* o = outf + (size_t)row * 512 + c0;
    *(float4*)o = make_float4(y[0], y[1], y[2], y[3]);
    *(float4*)(o + 4) = make_float4(y[4], y[5], y[6], y[7]);
  } else if (mode == 1) {
    float am = 0.f;
#pragma unroll
    for (int j = 0; j < 8; ++j) am = fmaxf(am, fabsf(y[j]));
#pragma unroll
    for (int m = 1; m < 64; m <<= 1) am = fmaxf(am, __shfl_xor(am, m));
    float amc = fmaxf(am, 1e-5f);
    float s = 127.0f / amc;
    unsigned long long pkt = 0;
#pragma unroll
    for (int j = 0; j < 8; ++j) {
      int q = (int)rintf(y[j] * s);
      pkt |= ((unsigned long long)(unsigned char)(signed char)q) << (8 * j);
    }
    *(unsigned long long*)(out8 + (size_t)row * 512 + c0) = pkt;
    if (lane == 0) dq[row] = amc * (1.0f / 127.0f);
  } else {
    v8s o;
#pragma unroll
    for (int j = 0; j < 8; ++j) o[j] = (short)f2bf(y[j]);
    *(v8s*)(outb + (size_t)row * 512 + c0) = o;
  }
}

// ---------------------------------------------------------------------------
// Wave-per-row int8 quant over bf16 rows of 2048 (32 elems/lane, 4 rows/blk).
// ---------------------------------------------------------------------------
__global__ __launch_bounds__(256) void rq2048_wave(
    const u16* __restrict__ h, signed char* __restrict__ out, float* __restrict__ dq) {
  const int tid = threadIdx.x;
  const int lane = tid & 63, wv = tid >> 6;
  const int row = blockIdx.x * 4 + wv;
  const u16* hr = h + (size_t)row * 2048;
  float vals[32];
  float am = 0.f;
#pragma unroll
  for (int g = 0; g < 4; ++g) {
    int c0 = g * 512 + lane * 8;
    v8s hv = *(const v8s*)(hr + c0);
#pragma unroll
    for (int j = 0; j < 8; ++j) {
      float v = bf2f((u16)hv[j]);
      vals[g * 8 + j] = v;
      am = fmaxf(am, fabsf(v));
    }
  }
#pragma unroll
  for (int m = 1; m < 64; m <<= 1) am = fmaxf(am, __shfl_xor(am, m));
  float amc = fmaxf(am, 1e-5f);
  float s = 127.0f / amc;
#pragma unroll
  for (int g = 0; g < 4; ++g) {
    unsigned long long pkt = 0;
#pragma unroll
    for (int j = 0; j < 8; ++j) {
      int q = (int)rintf(vals[g * 8 + j] * s);
      pkt |= ((unsigned long long)(unsigned char)(signed char)q) << (8 * j);
    }
    *(unsigned long long*)(out + (size_t)row * 2048 + g * 512 + lane * 8) = pkt;
  }
  if (lane == 0) dq[row] = amc * (1.0f / 127.0f);
}

// ---------------------------------------------------------------------------
// Wave-per-row int8 quant of [M,512] bf16 (4 rows/block).
// ---------------------------------------------------------------------------
__global__ __launch_bounds__(256) void rowquant_wave(
    const u16* __restrict__ in, signed char* __restrict__ out, float* __restrict__ dq) {
  const int tid = threadIdx.x;
  const int lane = tid & 63, wv = tid >> 6;
  const int row = blockIdx.x * 4 + wv;
  const int c0 = lane * 8;
  v8s xv = *(const v8s*)(in + (size_t)row * 512 + c0);
  float v[8];
  float am = 0.f;
#pragma unroll
  for (int j = 0; j < 8; ++j) {
    v[j] = bf2f((u16)xv[j]);
    am = fmaxf(am, fabsf(v[j]));
  }
#pragma unroll
  for (int m = 1; m < 64; m <<= 1) am = fmaxf(am, __shfl_xor(am, m));
  float amc = fmaxf(am, 1e-5f);
  float s = 127.0f / amc;
  unsigned long long pkt = 0;
#pragma unroll
  for (int j = 0; j < 8; ++j) {
    int q = (int)rintf(v[j] * s);
    pkt |= ((unsigned long long)(unsigned char)(signed char)q) << (8 * j);
  }
  *(unsigned long long*)(out + (size_t)row * 512 + c0) = pkt;
  if (lane == 0) dq[row] = amc * (1.0f / 127.0f);
}

// ---------------------------------------------------------------------------
// int8 GEMM: acc = (A i8[M,K] @ B i8[N,K]^T) * wsc * dq[m].
// 128xBN tile, BK=128, XCD swizzle.
// OM=0: bf16 out. OM=1: bf16 out = bf16(resid) + rscale*acc.
// OM=2: bf16 out = snake(acc) via tables ta/tb (FFN-up, N=2048).
// OM=3: acc + bias, scatter into fragment-packed kvqp (in_proj, N=1536).
// ---------------------------------------------------------------------------
template <int BN, int OM>
__global__ __launch_bounds__(256) void gemm_i8_t(
    const signed char* __restrict__ A, const signed char* __restrict__ B,
    const float* __restrict__ wsp, const float* __restrict__ adq,
    const u16* __restrict__ resid, float rscale,
    u16* __restrict__ outb, int N, int K,
    const float* __restrict__ ta, const float* __restrict__ tb,
    const float* __restrict__ bias) {
  constexpr int JF = BN / 32;
  __shared__ signed char As[16384];
  __shared__ signed char Bs[BN * 128];
  const int tid = threadIdx.x;
  int txc, tyc;
  xcd_tiles(txc, tyc);
  const int m0 = tyc << 7;
  const int n0 = txc * BN;
  const int lane = tid & 63;
  const int wv = tid >> 6;
  const int wr = (wv >> 1) << 6, wc = (wv & 1) * (16 * JF);
  const int r15 = lane & 15, khi = lane >> 4;
  const int srow = tid >> 3;
  const int sslot = (tid & 7) ^ (srow & 7);
  const signed char* Ag = A + (size_t)(m0 + srow) * K + sslot * 16;
  const signed char* Bg = B + (size_t)(n0 + srow) * K + sslot * 16;
  const size_t row32 = (size_t)32 * K;

  int aoff[4][2], boff[JF][2];
#pragma unroll
  for (int i = 0; i < 4; ++i) {
    int r = wr + i * 16 + r15;
#pragma unroll
    for (int s = 0; s < 2; ++s)
      aoff[i][s] = r * 128 + (((s << 2) + khi) ^ (r & 7)) * 16;
  }
#pragma unroll
  for (int j = 0; j < JF; ++j) {
    int c = wc + j * 16 + r15;
#pragma unroll
    for (int s = 0; s < 2; ++s)
      boff[j][s] = c * 128 + (((s << 2) + khi) ^ (c & 7)) * 16;
  }
  v4i acc[4][JF] = {};
  for (int k0 = 0; k0 < K; k0 += 128) {
    __syncthreads();
#pragma unroll
    for (int c = 0; c < 4; ++c)
      GLOAD_LDS(Ag + c * row32 + k0, As + c * 4096 + tid * 16);
#pragma unroll
    for (int c = 0; c < BN / 32; ++c)
      GLOAD_LDS(Bg + c * row32 + k0, Bs + c * 4096 + tid * 16);
    __syncthreads();
    v4i a[4][2], b[JF][2];
#pragma unroll
    for (int i = 0; i < 4; ++i) {
      a[i][0] = *(const v4i*)(As + aoff[i][0]);
      a[i][1] = *(const v4i*)(As + aoff[i][1]);
    }
#pragma unroll
    for (int j = 0; j < JF; ++j) {
      b[j][0] = *(const v4i*)(Bs + boff[j][0]);
      b[j][1] = *(const v4i*)(Bs + boff[j][1]);
    }
#pragma unroll
    for (int i = 0; i < 4; ++i)
#pragma unroll
      for (int j = 0; j < JF; ++j) {
        acc[i][j] = __builtin_amdgcn_mfma_i32_16x16x64_i8(a[i][0], b[j][0], acc[i][j], 0, 0, 0);
        acc[i][j] = __builtin_amdgcn_mfma_i32_16x16x64_i8(a[i][1], b[j][1], acc[i][j], 0, 0, 0);
      }
  }
  const float wsc = *wsp;
#pragma unroll
  for (int i = 0; i < 4; ++i) {
    int rb = m0 + wr + i * 16 + (khi << 2);
    float dqv[4];
#pragma unroll
    for (int rr = 0; rr < 4; ++rr) dqv[rr] = adq[rb + rr] * wsc;
#pragma unroll
    for (int j = 0; j < JF; ++j) {
      int col = n0 + wc + j * 16 + r15;
      float sa, sib, bv;
      if constexpr (OM == 2) { sa = ta[col]; sib = tb[col]; }
      if constexpr (OM == 3) { bv = bias[col]; }
#pragma unroll
      for (int rr = 0; rr < 4; ++rr) {
        float v = (float)acc[i][j][rr] * dqv[rr];
        if constexpr (OM == 3) {
          v += bv;
          int rowb = rb + rr;
          int tin = rowb & 31;
          int seg = col >> 9;           // 0=Q, 1=K, 2=V
          int cc = col & 511;
          int h2 = cc >> 6, d = cc & 63;
          size_t base = ((size_t)(((rowb >> 11) * 8 + h2) * 64 + ((rowb & 2047) >> 5))) * 6144;
          size_t off;
          if (seg == 0)
            off = (size_t)(8 + (d >> 4)) * 512 + ((((d >> 3) & 1) << 5) + tin) * 8 + (d & 7);
          else if (seg == 1)
            off = (size_t)(d >> 4) * 512 + ((((d >> 3) & 1) << 5) + tin) * 8 + (d & 7);
          else
            off = (size_t)(4 + ((d >> 5) << 1) + (tin >> 4)) * 512 +
                  ((((tin >> 3) & 1) << 5) + (d & 31)) * 8 + (tin & 7);
          outb[base + off] = f2bf(v);
        } else {
          size_t idx = (size_t)(rb + rr) * N + col;
          if constexpr (OM == 0) {
            outb[idx] = f2bf(v);
          } else if constexpr (OM == 1) {
            outb[idx] = f2bf(fmaf(rscale, v, bf2f(resid[idx])));
          } else {
            float sn = __sinf(sa * v);
            outb[idx] = f2bf(v + sn * sn * sib);
          }
        }
      }
    }
  }
}

// ---------------------------------------------------------------------------
// bf16 GEMM: acc = A bf16[M,K] @ B bf16[N,K]^T + bias. XCD swizzle.
// OM=1: bf16 out = bf16(resid) + acc + bias.  (out_proj only now)
// ---------------------------------------------------------------------------
template <int BN, int OM>
__global__ __launch_bounds__(256) void gemm_bf16_t(
    const u16* __restrict__ A, const u16* __restrict__ B,
    const float* __restrict__ bias, const u16* __restrict__ resid,
    u16* __restrict__ outb, int N, int K) {
  constexpr int JF = BN / 32;
  __shared__ signed char As[8192];
  __shared__ signed char Bs[BN * 64];
  const int tid = threadIdx.x;
  int txc, tyc;
  xcd_tiles(txc, tyc);
  const int m0 = tyc << 7;
  const int n0 = txc * BN;
  const int lane = tid & 63;
  const int wv = tid >> 6;
  const int wr = (wv >> 1) << 6, wc = (wv & 1) * (16 * JF);
  const int r15 = lane & 15, khi = lane >> 4;
  const int srow = tid >> 2;
  const int sslot = (tid & 3) ^ ((srow >> 1) & 3);
  const int K2 = K * 2;
  const signed char* Ag = (const signed char*)A + (size_t)(m0 + srow) * K2 + sslot * 16;
  const signed char* Bg = (const signed char*)B + (size_t)(n0 + srow) * K2 + sslot * 16;
  const size_t half = (size_t)64 * K2;

  int aoff[4], boff[JF];
#pragma unroll
  for (int i = 0; i < 4; ++i) {
    int r = wr + i * 16 + r15;
    aoff[i] = r * 64 + ((khi ^ ((r >> 1) & 3)) << 4);
  }
#pragma unroll
  for (int j = 0; j < JF; ++j) {
    int c = wc + j * 16 + r15;
    boff[j] = c * 64 + ((khi ^ ((c >> 1) & 3)) << 4);
  }
  v4f acc[4][JF] = {};
  for (int kb = 0; kb < K2; kb += 64) {
    __syncthreads();
    GLOAD_LDS(Ag + kb, As + tid * 16);
    GLOAD_LDS(Ag + half + kb, As + 4096 + tid * 16);
    GLOAD_LDS(Bg + kb, Bs + tid * 16);
    if constexpr (BN == 128) GLOAD_LDS(Bg + half + kb, Bs + 4096 + tid * 16);
    __syncthreads();
    v8s a[4], b[JF];
#pragma unroll
    for (int i = 0; i < 4; ++i) a[i] = *(const v8s*)(As + aoff[i]);
#pragma unroll
    for (int j = 0; j < JF; ++j) b[j] = *(const v8s*)(Bs + boff[j]);
#pragma unroll
    for (int i = 0; i < 4; ++i)
#pragma unroll
      for (int j = 0; j < JF; ++j)
        acc[i][j] = __builtin_amdgcn_mfma_f32_16x16x32_bf16(a[i], b[j], acc[i][j], 0, 0, 0);
  }
#pragma unroll
  for (int i = 0; i < 4; ++i) {
    int rb = m0 + wr + i * 16 + (khi << 2);
#pragma unroll
    for (int j = 0; j < JF; ++j) {
      int col = n0 + wc + j * 16 + r15;
      float bv = bias[col];
#pragma unroll
      for (int rr = 0; rr < 4; ++rr) {
        size_t idx = (size_t)(rb + rr) * N + col;
        float v = acc[i][j][rr] + bv;
        if constexpr (OM == 0) outb[idx] = f2bf(v);
        else outb[idx] = f2bf(bf2f(resid[idx]) + v);
      }
    }
  }
}

// ---------------------------------------------------------------------------
// Flash attention, swapped-operand 32x32 bf16 MFMA, LDS-staged K/V (dbuf),
// MAX-FREE softmax, k-split x1, bh-affinity XCD remap (all q-blocks of one
// bh land on the same XCD so its K/V stays in that XCD's L2).
// grid (16 qgroups, 32 bh) flat-remapped.
// ---------------------------------------------------------------------------
__global__ __launch_bounds__(256) void attn32(
    const u16* __restrict__ kvqp, u16* __restrict__ attno) {
  __shared__ u16 KV[2][4096];
  const int tid = threadIdx.x;
  const int lane = tid & 63;
  const int wv = tid >> 6;
  const int l31 = lane & 31;
  const int hi = lane >> 5;
  // bh-affinity remap: flat = qg + bh*16 (hardware x-major). XCD = flat & 7.
  const int flat = blockIdx.y * 16 + blockIdx.x;
  const int qg = flat >> 5;
  const int bh = (flat & 7) | (((flat >> 3) & 3) << 3);
  const int b = bh >> 3, h = bh & 7;
  const int qt = qg * 4 + wv;
  const int q0 = qt << 5;
  const float C = 0.18033688011112042f;  // 0.125 * log2(e)

  v8s qf[4];
  {
    const u16* qb = kvqp + ((size_t)(bh * 64 + qt)) * 6144 + lane * 8;
#pragma unroll
    for (int ks = 0; ks < 4; ++ks) qf[ks] = *(const v8s*)(qb + (8 + ks) * 512);
  }
  v16f o0 = {}, o1 = {};
  float l_run = 0.f;

  const u16* tb = kvqp + ((size_t)(bh * 64)) * 6144;

  GLOAD_LDS(tb + tid * 8, &KV[0][tid * 8]);
  GLOAD_LDS(tb + 2048 + tid * 8, &KV[0][2048 + tid * 8]);
  __syncthreads();

  int cur = 0;
  for (int t = 0; t < 64; ++t) {
    if (t < 63) {
      const u16* nb = tb + (size_t)(t + 1) * 6144;
      GLOAD_LDS(nb + tid * 8, &KV[cur ^ 1][tid * 8]);
      GLOAD_LDS(nb + 2048 + tid * 8, &KV[cur ^ 1][2048 + tid * 8]);
    }
    v8s kf[4], vf[4];
#pragma unroll
    for (int ks = 0; ks < 4; ++ks) kf[ks] = *(const v8s*)(&KV[cur][ks * 512 + lane * 8]);
#pragma unroll
    for (int j = 0; j < 4; ++j) vf[j] = *(const v8s*)(&KV[cur][2048 + j * 512 + lane * 8]);

    __builtin_amdgcn_s_setprio(1);
    v16f sacc = {};
#pragma unroll
    for (int ks = 0; ks < 4; ++ks)
      sacc = __builtin_amdgcn_mfma_f32_32x32x16_bf16(kf[ks], qf[ks], sacc, 0, 0, 0);
    __builtin_amdgcn_s_setprio(0);

    float s[16];
#pragma unroll
    for (int r = 0; r < 16; ++r) s[r] = exp2f(sacc[r] * C);

    {
      float a0 = (s[0] + s[1]) + (s[2] + s[3]);
      float a1 = (s[4] + s[5]) + (s[6] + s[7]);
      float a2 = (s[8] + s[9]) + (s[10] + s[11]);
      float a3 = (s[12] + s[13]) + (s[14] + s[15]);
      float ls = (a0 + a1) + (a2 + a3);
      float tsw = ls;
      asm("v_permlane32_swap_b32 %0, %1" : "+v"(tsw), "+v"(ls));
      l_run += ls + tsw;
    }

    unsigned pk[8];
#pragma unroll
    for (int g = 0; g < 8; ++g) {
      unsigned u;
      asm("v_cvt_pk_bf16_f32 %0, %1, %2" : "=v"(u) : "v"(s[2 * g]), "v"(s[2 * g + 1]));
      pk[g] = u;
    }
    asm("v_permlane32_swap_b32 %0, %1" : "+v"(pk[2]), "+v"(pk[0]));
    asm("v_permlane32_swap_b32 %0, %1" : "+v"(pk[3]), "+v"(pk[1]));
    asm("v_permlane32_swap_b32 %0, %1" : "+v"(pk[6]), "+v"(pk[4]));
    asm("v_permlane32_swap_b32 %0, %1" : "+v"(pk[7]), "+v"(pk[5]));
    v4i w0, w1;
    w0[0] = pk[0]; w0[1] = pk[1]; w0[2] = pk[2]; w0[3] = pk[3];
    w1[0] = pk[4]; w1[1] = pk[5]; w1[2] = pk[6]; w1[3] = pk[7];
    v8s pf0 = *(v8s*)&w0;
    v8s pf1 = *(v8s*)&w1;

    __builtin_amdgcn_s_setprio(1);
    o0 = __builtin_amdgcn_mfma_f32_32x32x16_bf16(vf[0], pf0, o0, 0, 0, 0);
    o0 = __builtin_amdgcn_mfma_f32_32x32x16_bf16(vf[1], pf1, o0, 0, 0, 0);
    o1 = __builtin_amdgcn_mfma_f32_32x32x16_bf16(vf[2], pf0, o1, 0, 0, 0);
    o1 = __builtin_amdgcn_mfma_f32_32x32x16_bf16(vf[3], pf1, o1, 0, 0, 0);
    __builtin_amdgcn_s_setprio(0);

    __syncthreads();
    cur ^= 1;
  }

  float inv = 1.0f / l_run;
  u16* orow = attno + (size_t)(b * 2048 + q0 + l31) * 512 + h * 64;
#pragma unroll
  for (int dt = 0; dt < 2; ++dt) {
#pragma unroll
    for (int g = 0; g < 8; ++g) {
      int d = dt * 32 + ((2 * g) & 3) + 8 * (g >> 1) + 4 * hi;
      float a = (dt ? o1[2 * g] : o0[2 * g]) * inv;
      float bv = (dt ? o1[2 * g + 1] : o0[2 * g + 1]) * inv;
      unsigned u;
      asm("v_cvt_pk_bf16_f32 %0, %1, %2" : "=v"(u) : "v"(a), "v"(bv));
      *(unsigned*)(orow + d) = u;
    }
  }
}

// ---------------------------------------------------------------------------
// Fused GLU + depthwise conv(K=31) + BN + snake. In: g3 bf16 [8192,1024].
// Out: bf16 [8192,512]. Block: (chgroup 64, t-tile 128, batch).
// ---------------------------------------------------------------------------
__global__ __launch_bounds__(256) void dwconv_fused(
    const u16* __restrict__ g3, const float* __restrict__ dww,
    const float* __restrict__ dwb, const float* __restrict__ bng,
    const float* __restrict__ bnb, const float* __restrict__ bnm,
    const float* __restrict__ bnv, const float* __restrict__ la,
    const float* __restrict__ lb, u16* __restrict__ outp) {
  __shared__ float IN[160 * 64];
  __shared__ float WT[1984];
  __shared__ float PRM[4][64];
  const int tid = threadIdx.x;
  const int cg = blockIdx.x << 6;
  const int t0 = blockIdx.y << 7;
  const int bb = blockIdx.z;

  if (tid < 64) {
    int c = cg + tid;
    float sc = bng[c] / sqrtf(bnv[c] + 1e-5f);
    PRM[0][tid] = sc;
    PRM[1][tid] = (dwb[c] - bnm[c]) * sc + bnb[c];
    PRM[2][tid] = __expf(la[c]);
    PRM[3][tid] = 1.0f / (__expf(lb[c]) + 1e-9f);
  }
  for (int i = tid; i < 1984; i += 256) WT[i] = dww[cg * 31 + i];

#pragma unroll
  for (int p = 0; p < 5; ++p) {
    int r = p * 32 + (tid >> 3);
    int t = t0 - 16 + r;
    int c8 = (tid & 7) << 3;
    float4 lo = make_float4(0.f, 0.f, 0.f, 0.f);
    float4 hv = make_float4(0.f, 0.f, 0.f, 0.f);
    if (t >= 0 && t < 2048) {
      const u16* rp = g3 + ((size_t)(bb * 2048 + t)) * 1024 + cg + c8;
      v8s a8 = *(const v8s*)rp;
      v8s g8 = *(const v8s*)(rp + 512);
      float va[8];
#pragma unroll
      for (int j = 0; j < 8; ++j) {
        float fa = bf2f((u16)a8[j]);
        float fg = bf2f((u16)g8[j]);
        va[j] = fa / (1.f + __expf(-fg));
      }
      lo = make_float4(va[0], va[1], va[2], va[3]);
      hv = make_float4(va[4], va[5], va[6], va[7]);
    }
    *(float4*)&IN[r * 64 + c8] = lo;
    *(float4*)&IN[r * 64 + c8 + 4] = hv;
  }
  __syncthreads();

  const int ch = tid & 63;
  const int tg = tid >> 6;
  const float sc = PRM[0][ch], sh = PRM[1][ch], sa = PRM[2][ch], sib = PRM[3][ch];
  float w[31];
#pragma unroll
  for (int k = 0; k < 31; ++k) w[k] = WT[ch * 31 + k];

  for (int pass = 0; pass < 4; ++pass) {
    int tl = pass * 32 + tg * 8;
    float x[38];
#pragma unroll
    for (int i = 0; i < 38; ++i) x[i] = IN[(tl + 1 + i) * 64 + ch];
    float acc[8] = {0.f, 0.f, 0.f, 0.f, 0.f, 0.f, 0.f, 0.f};
#pragma unroll
    for (int k = 0; k < 31; ++k)
#pragma unroll
      for (int j = 0; j < 8; ++j) acc[j] = fmaf(x[k + j], w[k], acc[j]);
#pragma unroll
    for (int j = 0; j < 8; ++j) {
      float v = acc[j] * sc + sh;
      float s = __sinf(sa * v);
      v += s * s * sib;
      outp[((size_t)(bb * 2048 + t0 + tl + j)) * 512 + cg + ch] = f2bf(v);
    }
  }
}

// ---------------------------------------------------------------------------
extern "C" void kernel_launch(void* const* d_in, const int* in_sizes, int n_in,
                              void* d_out, int out_size, void* d_ws, size_t ws_size,
                              hipStream_t stream) {
  const float* x_in = (const float*)d_in[0];
  const float* ff1_norm_w = (const float*)d_in[1];
  const float* ff1_w1 = (const float*)d_in[2];
  const float* ff1_a = (const float*)d_in[3];
  const float* ff1_b = (const float*)d_in[4];
  const float* ff1_w2 = (const float*)d_in[5];
  const float* attn_norm_w = (const float*)d_in[6];
  const float* in_proj_w = (const float*)d_in[7];
  const float* in_proj_b = (const float*)d_in[8];
  const float* out_proj_w = (const float*)d_in[9];
  const float* out_proj_b = (const float*)d_in[10];
  const float* conv_norm_w = (const float*)d_in[11];
  const float* pw1_w = (const float*)d_in[12];
  const float* dw_w = (const float*)d_in[13];
  const float* dw_b = (const float*)d_in[14];
  const float* bn_g = (const float*)d_in[15];
  const float* bn_b = (const float*)d_in[16];
  const float* bn_m = (const float*)d_in[17];
  const float* bn_v = (const float*)d_in[18];
  const float* snake_a = (const float*)d_in[19];
  const float* snake_b = (const float*)d_in[20];
  const float* pw2_w = (const float*)d_in[21];
  const float* ff2_norm_w = (const float*)d_in[22];
  const float* ff2_w1 = (const float*)d_in[23];
  const float* ff2_a = (const float*)d_in[24];
  const float* ff2_b = (const float*)d_in[25];
  const float* ff2_w2 = (const float*)d_in[26];
  const float* final_norm_w = (const float*)d_in[27];
  float* out = (float*)d_out;

  char* ws = (char*)d_ws;
  u16* x_bf = (u16*)(ws + 0);                          // 8 MiB  (bf16 of x_in)
  u16* x_cur = (u16*)(ws + 8388608);                   // 8 MiB  (bf16 residual)
  // attn phase:
  u16* kvqp = (u16*)(ws + 41943040);                   // 24 MiB (packed Q/K/V)
  u16* attno = (u16*)(ws + 100663296);                 // 8 MiB
  // FFN phase:
  u16* h_b = (u16*)(ws + 16777216);                    // 32 MiB
  // conv phase:
  u16* g3b = (u16*)(ws + 16777216);                    // 16 MiB
  u16* convout = (u16*)(ws + 50331648);                // 8 MiB
  signed char* a8a = (signed char*)(ws + 83886080);    // 4 MiB
  signed char* a8b = (signed char*)(ws + 88080384);    // 16 MiB
  u16* xnb = (u16*)(ws + 104857600);                   // 8 MiB (unused now)
  signed char* wq = (signed char*)(ws + 113246208);    // ternary 4.75 MiB + in_proj i8
  signed char* wq_w1 = wq;
  signed char* wq_w2 = wq + 1048576;
  signed char* wq_p1 = wq + 2097152;
  signed char* wq_p2 = wq + 2621440;
  signed char* wq_f21 = wq + 2883584;
  signed char* wq_f22 = wq + 3932160;
  signed char* wq_ip = wq + 4980736;                   // 786432 B (int8 in_proj)
  u16* wb = (u16*)(ws + 119013376);                    // 512 KiB (bf16 out_proj)
  u16* wb_op = wb;
  float* scales = (float*)(ws + 120324096);            // 7 floats
  float* partials = (float*)(ws + 120324352);          // 7*64 floats
  float* ascale = (float*)(ws + 120325888);            // 32 KiB
  float* tabs = (float*)(ws + 120358912);              // 32 KiB

  // --- weight prep ---
  wabs_stage1<<<448, 256, 0, stream>>>(ff1_w1, ff1_w2, pw1_w, pw2_w, ff2_w1, ff2_w2,
                                       in_proj_w, partials);
  wquant_all<<<dim3(128, 7), 256, 0, stream>>>(ff1_w1, ff1_w2, pw1_w, pw2_w, ff2_w1, ff2_w2,
                                               in_proj_w, partials, scales, wq);
  wcvt_tabs<<<264, 256, 0, stream>>>(out_proj_w, wb, ff1_a, ff1_b, ff2_a, ff2_b, tabs);

  // --- FFN1: x_cur = x + 0.5*ffn(x)  (snake fused into up-GEMM epilogue) ---
  rmsnorm_f32x<<<2048, 256, 0, stream>>>(x_in, ff1_norm_w, a8a, x_bf, ascale);
  gemm_i8_t<128, 2><<<dim3(16, 64), 256, 0, stream>>>(
      a8a, wq_w1, scales + 0, ascale, nullptr, 1.0f, h_b, 2048, 512, tabs, tabs + 2048, nullptr);
  rq2048_wave<<<2048, 256, 0, stream>>>(h_b, a8b, ascale);
  gemm_i8_t<64, 1><<<dim3(8, 64), 256, 0, stream>>>(
      a8b, wq_w2, scales + 1, ascale, x_bf, 0.5f, x_cur, 512, 2048, nullptr, nullptr, nullptr);

  // --- MHA: x_cur += mha(x_cur)  (int8 in_proj scatters packed kvqp) ---
  rmsnorm_wave<<<2048, 256, 0, stream>>>(x_cur, attn_norm_w, 1, nullptr, a8a, nullptr, ascale);
  gemm_i8_t<128, 3><<<dim3(12, 64), 256, 0, stream>>>(
      a8a, wq_ip, scales + 6, ascale, nullptr, 1.0f, kvqp, 1536, 512, nullptr, nullptr,
      in_proj_b);
  attn32<<<dim3(16, 32), 256, 0, stream>>>(kvqp, attno);
  gemm_bf16_t<64, 1><<<dim3(8, 64), 256, 0, stream>>>(
      attno, wb_op, out_proj_b, x_cur, x_cur, 512, 512);

  // --- conv branch: x_cur += conv(x_cur) ---
  rmsnorm_wave<<<2048, 256, 0, stream>>>(x_cur, conv_norm_w, 1, nullptr, a8a, nullptr, ascale);
  gemm_i8_t<128, 0><<<dim3(8, 64), 256, 0, stream>>>(
      a8a, wq_p1, scales + 2, ascale, nullptr, 1.0f, g3b, 1024, 512, nullptr, nullptr, nullptr);
  dwconv_fused<<<dim3(8, 16, 4), 256, 0, stream>>>(g3b, dw_w, dw_b, bn_g, bn_b, bn_m, bn_v,
                                                   snake_a, snake_b, convout);
  rowquant_wave<<<2048, 256, 0, stream>>>(convout, a8a, ascale);
  gemm_i8_t<64, 1><<<dim3(8, 64), 256, 0, stream>>>(
      a8a, wq_p2, scales + 3, ascale, x_cur, 1.0f, x_cur, 512, 512, nullptr, nullptr, nullptr);

  // --- FFN2: x_cur += 0.5*ffn(x_cur) ---
  rmsnorm_wave<<<2048, 256, 0, stream>>>(x_cur, ff2_norm_w, 1, nullptr, a8a, nullptr, ascale);
  gemm_i8_t<128, 2><<<dim3(16, 64), 256, 0, stream>>>(
      a8a, wq_f21, scales + 4, ascale, nullptr, 1.0f, h_b, 2048, 512, tabs + 4096, tabs + 6144,
      nullptr);
  rq2048_wave<<<2048, 256, 0, stream>>>(h_b, a8b, ascale);
  gemm_i8_t<64, 1><<<dim3(8, 64), 256, 0, stream>>>(
      a8b, wq_f22, scales + 5, ascale, x_cur, 0.5f, x_cur, 512, 2048, nullptr, nullptr, nullptr);

  // --- final rmsnorm -> out (f32) ---
  rmsnorm_wave<<<2048, 256, 0, stream>>>(x_cur, final_norm_w, 0, out, nullptr, nullptr, nullptr);
}

// Round 21
// 290.150 us; speedup vs baseline: 1.0088x; 1.0088x over previous
//
#include <hip/hip_runtime.h>
#include <math.h>

// ---------------------------------------------------------------------------
// ConformerBlock MFMA implementation.
// B=4, T=2048, D=512, H=8, hd=64, K=31.  M = B*T = 8192.
// Bitlinear GEMMs + in_proj: int8 MFMA (BK=128, XCD-swizzled). bf16 residual
// stream. Attention: swapped-operand 32x32 MFMA, LDS-staged K/V (dbuf),
// max-free softmax with C-prescaled Q, k-split x1, bh-affinity XCD remap.
// in_proj scatters packed kvqp; FFN-up applies snake in epilogue.
// ---------------------------------------------------------------------------

typedef int   v4i __attribute__((ext_vector_type(4)));
typedef float v4f __attribute__((ext_vector_type(4)));
typedef float v16f __attribute__((ext_vector_type(16)));
typedef short v8s __attribute__((ext_vector_type(8)));
typedef unsigned short u16;

#define GLOAD_LDS(g, l) __builtin_amdgcn_global_load_lds( \
    (const __attribute__((address_space(1))) void*)(g),   \
    (__attribute__((address_space(3))) void*)(l), 16, 0, 0)

__device__ __forceinline__ float blk_sum256(float v, float* sm) {
#pragma unroll
  for (int m = 32; m; m >>= 1) v += __shfl_xor(v, m);
  int w = threadIdx.x >> 6;
  __syncthreads();
  if ((threadIdx.x & 63) == 0) sm[w] = v;
  __syncthreads();
  return sm[0] + sm[1] + sm[2] + sm[3];
}

__device__ __forceinline__ float blk_max256(float v, float* sm) {
#pragma unroll
  for (int m = 32; m; m >>= 1) v = fmaxf(v, __shfl_xor(v, m));
  int w = threadIdx.x >> 6;
  __syncthreads();
  if ((threadIdx.x & 63) == 0) sm[w] = v;
  __syncthreads();
  return fmaxf(fmaxf(sm[0], sm[1]), fmaxf(sm[2], sm[3]));
}

__device__ __forceinline__ u16 f2bf(float f) {
  union { float f; unsigned u; } x;
  x.f = f;
  unsigned r = x.u + 0x7fffu + ((x.u >> 16) & 1u);
  return (u16)(r >> 16);
}

__device__ __forceinline__ float bf2f(u16 u) {
  union { unsigned u; float f; } x;
  x.u = ((unsigned)u) << 16;
  return x.f;
}

// XCD-aware bijective block remap (nwg divisible by 8 for all our grids).
__device__ __forceinline__ void xcd_tiles(int& tx, int& ty) {
  int nx = gridDim.x;
  int flat = blockIdx.y * nx + blockIdx.x;
  int nwg = nx * gridDim.y;
  int cpx = nwg >> 3;
  int swz = (flat & 7) * cpx + (flat >> 3);
  ty = swz / nx;
  tx = swz - ty * nx;
}

// ---------------------------------------------------------------------------
// Weight reductions: widx 0..5 ternary (sum|w| -> mean), widx 6 in_proj
// (max|w| for int8 quant). grid = 7*64.
// ---------------------------------------------------------------------------
__global__ __launch_bounds__(256) void wabs_stage1(
    const float* __restrict__ w0, const float* __restrict__ w1,
    const float* __restrict__ w2, const float* __restrict__ w3,
    const float* __restrict__ w4, const float* __restrict__ w5,
    const float* __restrict__ w6, float* __restrict__ part) {
  __shared__ float sm[4];
  const float* ws[7] = {w0, w1, w2, w3, w4, w5, w6};
  const int ns[7] = {1048576, 1048576, 524288, 262144, 1048576, 1048576, 786432};
  int widx = blockIdx.x >> 6;
  int chunk = blockIdx.x & 63;
  const float* w = ws[widx];
  int n = ns[widx];
  if (widx < 6) {
    float s = 0.f;
    for (int i = chunk * 256 + threadIdx.x; i < n; i += 64 * 256) s += fabsf(w[i]);
    s = blk_sum256(s, sm);
    if (threadIdx.x == 0) part[widx * 64 + chunk] = s;
  } else {
    float s = 0.f;
    for (int i = chunk * 256 + threadIdx.x; i < n; i += 64 * 256) s = fmaxf(s, fabsf(w[i]));
    s = blk_max256(s, sm);
    if (threadIdx.x == 0) part[widx * 64 + chunk] = s;
  }
}

// stage2 folded in: every block recomputes the 64-partial reduce for its widx.
__global__ __launch_bounds__(256) void wquant_all(
    const float* __restrict__ w0, const float* __restrict__ w1,
    const float* __restrict__ w2, const float* __restrict__ w3,
    const float* __restrict__ w4, const float* __restrict__ w5,
    const float* __restrict__ w6,
    const float* __restrict__ part, float* __restrict__ scales,
    signed char* __restrict__ out) {
  const float* ws[7] = {w0, w1, w2, w3, w4, w5, w6};
  const int ns[7] = {1048576, 1048576, 524288, 262144, 1048576, 1048576, 786432};
  const int offs[7] = {0, 1048576, 2097152, 2621440, 2883584, 3932160, 4980736};
  int widx = blockIdx.y;
  const float* w = ws[widx];
  int n = ns[widx];
  signed char* o = out + offs[widx];
  float s, clipv;
  if (widx < 6) {
    float ssum = 0.f;
#pragma unroll 8
    for (int i = 0; i < 64; ++i) ssum += part[widx * 64 + i];
    float wsc = fmaxf(ssum / (float)n, 1e-5f);
    if (blockIdx.x == 0 && threadIdx.x == 0) scales[widx] = wsc;
    s = 1.0f / wsc;
    clipv = 1.f;
  } else {
    float am = 0.f;
#pragma unroll 8
    for (int i = 0; i < 64; ++i) am = fmaxf(am, part[widx * 64 + i]);
    float step = fmaxf(am, 1e-5f) * (1.0f / 127.0f);
    if (blockIdx.x == 0 && threadIdx.x == 0) scales[widx] = step;
    s = 1.0f / step;
    clipv = 127.f;
  }
  for (int i = blockIdx.x * 256 + threadIdx.x; i < n; i += 128 * 256)
    o[i] = (signed char)(int)fminf(fmaxf(rintf(w[i] * s), -clipv), clipv);
}

// bf16 out_proj convert (x4 vectorized) + snake exp tables in one launch.
__global__ __launch_bounds__(256) void wcvt_tabs(
    const float* __restrict__ op, u16* __restrict__ wb,
    const float* __restrict__ a1, const float* __restrict__ b1,
    const float* __restrict__ a2, const float* __restrict__ b2,
    float* __restrict__ tabs) {
  int bid = blockIdx.x;
  if (bid < 256) {
    int i = bid * 256 + threadIdx.x;
    float4 f = *(const float4*)(op + (size_t)i * 4);
    u16* dst = wb + (size_t)i * 4;
    dst[0] = f2bf(f.x); dst[1] = f2bf(f.y); dst[2] = f2bf(f.z); dst[3] = f2bf(f.w);
  } else {
    int i = (bid - 256) * 256 + threadIdx.x;
    if (i < 2048) {
      tabs[i] = __expf(a1[i]);
      tabs[2048 + i] = 1.0f / (__expf(b1[i]) + 1e-9f);
      tabs[4096 + i] = __expf(a2[i]);
      tabs[6144 + i] = 1.0f / (__expf(b2[i]) + 1e-9f);
    }
  }
}

// ---------------------------------------------------------------------------
// Wave-per-row RMSNorm over f32 rows of 512 (4 rows/block): emits bf16 copy
// of x AND int8 quant + dq.
// ---------------------------------------------------------------------------
__global__ __launch_bounds__(256) void rmsnorm_f32x(
    const float* __restrict__ x, const float* __restrict__ w,
    signed char* __restrict__ out8, u16* __restrict__ xbf,
    float* __restrict__ dq) {
  const int tid = threadIdx.x;
  const int lane = tid & 63, wv = tid >> 6;
  const int row = blockIdx.x * 4 + wv;
  const int c0 = lane * 8;
  const float* xr = x + (size_t)row * 512 + c0;
  float4 f0 = *(const float4*)xr;
  float4 f1 = *(const float4*)(xr + 4);
  float fin[8] = {f0.x, f0.y, f0.z, f0.w, f1.x, f1.y, f1.z, f1.w};
  v8s xb;
  float v[8];
  float ss = 0.f;
#pragma unroll
  for (int j = 0; j < 8; ++j) {
    u16 b = f2bf(fin[j]);
    xb[j] = (short)b;
    v[j] = bf2f(b);
    ss = fmaf(v[j], v[j], ss);
  }
  *(v8s*)(xbf + (size_t)row * 512 + c0) = xb;
#pragma unroll
  for (int m = 1; m < 64; m <<= 1) ss += __shfl_xor(ss, m);
  float sc = 1.0f / sqrtf(ss * (1.0f / 512.0f) + 1e-6f);
  float4 w0 = *(const float4*)(w + c0);
  float4 w1 = *(const float4*)(w + c0 + 4);
  float wv8[8] = {w0.x, w0.y, w0.z, w0.w, w1.x, w1.y, w1.z, w1.w};
  float y[8];
  float am = 0.f;
#pragma unroll
  for (int j = 0; j < 8; ++j) {
    y[j] = v[j] * sc * wv8[j];
    am = fmaxf(am, fabsf(y[j]));
  }
#pragma unroll
  for (int m = 1; m < 64; m <<= 1) am = fmaxf(am, __shfl_xor(am, m));
  float amc = fmaxf(am, 1e-5f);
  float s = 127.0f / amc;
  unsigned long long pkt = 0;
#pragma unroll
  for (int j = 0; j < 8; ++j) {
    int q = (int)rintf(y[j] * s);
    pkt |= ((unsigned long long)(unsigned char)(signed char)q) << (8 * j);
  }
  *(unsigned long long*)(out8 + (size_t)row * 512 + c0) = pkt;
  if (lane == 0) dq[row] = amc * (1.0f / 127.0f);
}

// ---------------------------------------------------------------------------
// Wave-per-row RMSNorm over bf16 rows of 512 (4 rows/block).
// mode 0: f32 out.  mode 1: int8-quant out + dq.  mode 2: bf16 out.
// ---------------------------------------------------------------------------
__global__ __launch_bounds__(256) void rmsnorm_wave(
    const u16* __restrict__ x, const float* __restrict__ w, int mode,
    float* __restrict__ outf, signed char* __restrict__ out8,
    u16* __restrict__ outb, float* __restrict__ dq) {
  const int tid = threadIdx.x;
  const int lane = tid & 63, wv = tid >> 6;
  const int row = blockIdx.x * 4 + wv;
  const int c0 = lane * 8;
  v8s xv = *(const v8s*)(x + (size_t)row * 512 + c0);
  float v[8];
  float ss = 0.f;
#pragma unroll
  for (int j = 0; j < 8; ++j) {
    v[j] = bf2f((u16)xv[j]);
    ss = fmaf(v[j], v[j], ss);
  }
#pragma unroll
  for (int m = 1; m < 64; m <<= 1) ss += __shfl_xor(ss, m);
  float sc = 1.0f / sqrtf(ss * (1.0f / 512.0f) + 1e-6f);
  float4 w0 = *(const float4*)(w + c0);
  float4 w1 = *(const float4*)(w + c0 + 4);
  float wv8[8] = {w0.x, w0.y, w0.z, w0.w, w1.x, w1.y, w1.z, w1.w};
  float y[8];
#pragma unroll
  for (int j = 0; j < 8; ++j) y[j] = v[j] * sc * wv8[j];
  if (mode == 0) {
    float* o = outf + (size_t)row * 512 + c0;
    *(float4*)o = make_float4(y[0], y[1], y[2], y[3]);
    *(float4*)(o + 4) = make_float4(y[4], y[5], y[6], y[7]);
  } else if (mode == 1) {
    float am = 0.f;
#pragma unroll
    for (int j = 0; j < 8; ++j) am = fmaxf(am, fabsf(y[j]));
#pragma unroll
    for (int m = 1; m < 64; m <<= 1) am = fmaxf(am, __shfl_xor(am, m));
    float amc = fmaxf(am, 1e-5f);
    float s = 127.0f / amc;
    unsigned long long pkt = 0;
#pragma unroll
    for (int j = 0; j < 8; ++j) {
      int q = (int)rintf(y[j] * s);
      pkt |= ((unsigned long long)(unsigned char)(signed char)q) << (8 * j);
    }
    *(unsigned long long*)(out8 + (size_t)row * 512 + c0) = pkt;
    if (lane == 0) dq[row] = amc * (1.0f / 127.0f);
  } else {
    v8s o;
#pragma unroll
    for (int j = 0; j < 8; ++j) o[j] = (short)f2bf(y[j]);
    *(v8s*)(outb + (size_t)row * 512 + c0) = o;
  }
}

// ---------------------------------------------------------------------------
// Wave-per-row int8 quant over bf16 rows of 2048 (32 elems/lane, 4 rows/blk).
// ---------------------------------------------------------------------------
__global__ __launch_bounds__(256) void rq2048_wave(
    const u16* __restrict__ h, signed char* __restrict__ out, float* __restrict__ dq) {
  const int tid = threadIdx.x;
  const int lane = tid & 63, wv = tid >> 6;
  const int row = blockIdx.x * 4 + wv;
  const u16* hr = h + (size_t)row * 2048;
  float vals[32];
  float am = 0.f;
#pragma unroll
  for (int g = 0; g < 4; ++g) {
    int c0 = g * 512 + lane * 8;
    v8s hv = *(const v8s*)(hr + c0);
#pragma unroll
    for (int j = 0; j < 8; ++j) {
      float v = bf2f((u16)hv[j]);
      vals[g * 8 + j] = v;
      am = fmaxf(am, fabsf(v));
    }
  }
#pragma unroll
  for (int m = 1; m < 64; m <<= 1) am = fmaxf(am, __shfl_xor(am, m));
  float amc = fmaxf(am, 1e-5f);
  float s = 127.0f / amc;
#pragma unroll
  for (int g = 0; g < 4; ++g) {
    unsigned long long pkt = 0;
#pragma unroll
    for (int j = 0; j < 8; ++j) {
      int q = (int)rintf(vals[g * 8 + j] * s);
      pkt |= ((unsigned long long)(unsigned char)(signed char)q) << (8 * j);
    }
    *(unsigned long long*)(out + (size_t)row * 2048 + g * 512 + lane * 8) = pkt;
  }
  if (lane == 0) dq[row] = amc * (1.0f / 127.0f);
}

// ---------------------------------------------------------------------------
// Wave-per-row int8 quant of [M,512] bf16 (4 rows/block).
// ---------------------------------------------------------------------------
__global__ __launch_bounds__(256) void rowquant_wave(
    const u16* __restrict__ in, signed char* __restrict__ out, float* __restrict__ dq) {
  const int tid = threadIdx.x;
  const int lane = tid & 63, wv = tid >> 6;
  const int row = blockIdx.x * 4 + wv;
  const int c0 = lane * 8;
  v8s xv = *(const v8s*)(in + (size_t)row * 512 + c0);
  float v[8];
  float am = 0.f;
#pragma unroll
  for (int j = 0; j < 8; ++j) {
    v[j] = bf2f((u16)xv[j]);
    am = fmaxf(am, fabsf(v[j]));
  }
#pragma unroll
  for (int m = 1; m < 64; m <<= 1) am = fmaxf(am, __shfl_xor(am, m));
  float amc = fmaxf(am, 1e-5f);
  float s = 127.0f / amc;
  unsigned long long pkt = 0;
#pragma unroll
  for (int j = 0; j < 8; ++j) {
    int q = (int)rintf(v[j] * s);
    pkt |= ((unsigned long long)(unsigned char)(signed char)q) << (8 * j);
  }
  *(unsigned long long*)(out + (size_t)row * 512 + c0) = pkt;
  if (lane == 0) dq[row] = amc * (1.0f / 127.0f);
}

// ---------------------------------------------------------------------------
// int8 GEMM: acc = (A i8[M,K] @ B i8[N,K]^T) * wsc * dq[m].
// 128xBN tile, BK=128, XCD swizzle.
// OM=0: bf16 out. OM=1: bf16 out = bf16(resid) + rscale*acc.
// OM=2: bf16 out = snake(acc) via tables ta/tb (FFN-up, N=2048).
// OM=3: acc + bias, scatter into fragment-packed kvqp (in_proj, N=1536);
//       Q segment is pre-scaled by C = 0.125*log2(e) for max-free softmax.
// ---------------------------------------------------------------------------
template <int BN, int OM>
__global__ __launch_bounds__(256) void gemm_i8_t(
    const signed char* __restrict__ A, const signed char* __restrict__ B,
    const float* __restrict__ wsp, const float* __restrict__ adq,
    const u16* __restrict__ resid, float rscale,
    u16* __restrict__ outb, int N, int K,
    const float* __restrict__ ta, const float* __restrict__ tb,
    const float* __restrict__ bias) {
  constexpr int JF = BN / 32;
  __shared__ signed char As[16384];
  __shared__ signed char Bs[BN * 128];
  const int tid = threadIdx.x;
  int txc, tyc;
  xcd_tiles(txc, tyc);
  const int m0 = tyc << 7;
  const int n0 = txc * BN;
  const int lane = tid & 63;
  const int wv = tid >> 6;
  const int wr = (wv >> 1) << 6, wc = (wv & 1) * (16 * JF);
  const int r15 = lane & 15, khi = lane >> 4;
  const int srow = tid >> 3;
  const int sslot = (tid & 7) ^ (srow & 7);
  const signed char* Ag = A + (size_t)(m0 + srow) * K + sslot * 16;
  const signed char* Bg = B + (size_t)(n0 + srow) * K + sslot * 16;
  const size_t row32 = (size_t)32 * K;

  int aoff[4][2], boff[JF][2];
#pragma unroll
  for (int i = 0; i < 4; ++i) {
    int r = wr + i * 16 + r15;
#pragma unroll
    for (int s = 0; s < 2; ++s)
      aoff[i][s] = r * 128 + (((s << 2) + khi) ^ (r & 7)) * 16;
  }
#pragma unroll
  for (int j = 0; j < JF; ++j) {
    int c = wc + j * 16 + r15;
#pragma unroll
    for (int s = 0; s < 2; ++s)
      boff[j][s] = c * 128 + (((s << 2) + khi) ^ (c & 7)) * 16;
  }
  v4i acc[4][JF] = {};
  for (int k0 = 0; k0 < K; k0 += 128) {
    __syncthreads();
#pragma unroll
    for (int c = 0; c < 4; ++c)
      GLOAD_LDS(Ag + c * row32 + k0, As + c * 4096 + tid * 16);
#pragma unroll
    for (int c = 0; c < BN / 32; ++c)
      GLOAD_LDS(Bg + c * row32 + k0, Bs + c * 4096 + tid * 16);
    __syncthreads();
    v4i a[4][2], b[JF][2];
#pragma unroll
    for (int i = 0; i < 4; ++i) {
      a[i][0] = *(const v4i*)(As + aoff[i][0]);
      a[i][1] = *(const v4i*)(As + aoff[i][1]);
    }
#pragma unroll
    for (int j = 0; j < JF; ++j) {
      b[j][0] = *(const v4i*)(Bs + boff[j][0]);
      b[j][1] = *(const v4i*)(Bs + boff[j][1]);
    }
#pragma unroll
    for (int i = 0; i < 4; ++i)
#pragma unroll
      for (int j = 0; j < JF; ++j) {
        acc[i][j] = __builtin_amdgcn_mfma_i32_16x16x64_i8(a[i][0], b[j][0], acc[i][j], 0, 0, 0);
        acc[i][j] = __builtin_amdgcn_mfma_i32_16x16x64_i8(a[i][1], b[j][1], acc[i][j], 0, 0, 0);
      }
  }
  const float wsc = *wsp;
#pragma unroll
  for (int i = 0; i < 4; ++i) {
    int rb = m0 + wr + i * 16 + (khi << 2);
    float dqv[4];
#pragma unroll
    for (int rr = 0; rr < 4; ++rr) dqv[rr] = adq[rb + rr] * wsc;
#pragma unroll
    for (int j = 0; j < JF; ++j) {
      int col = n0 + wc + j * 16 + r15;
      float sa, sib, bv;
      if constexpr (OM == 2) { sa = ta[col]; sib = tb[col]; }
      if constexpr (OM == 3) { bv = bias[col]; }
#pragma unroll
      for (int rr = 0; rr < 4; ++rr) {
        float v = (float)acc[i][j][rr] * dqv[rr];
        if constexpr (OM == 3) {
          v += bv;
          int rowb = rb + rr;
          int tin = rowb & 31;
          int seg = col >> 9;           // 0=Q, 1=K, 2=V
          int cc = col & 511;
          int h2 = cc >> 6, d = cc & 63;
          if (seg == 0) v *= 0.18033688011112042f;  // fold 0.125*log2(e) into Q
          size_t base = ((size_t)(((rowb >> 11) * 8 + h2) * 64 + ((rowb & 2047) >> 5))) * 6144;
          size_t off;
          if (seg == 0)
            off = (size_t)(8 + (d >> 4)) * 512 + ((((d >> 3) & 1) << 5) + tin) * 8 + (d & 7);
          else if (seg == 1)
            off = (size_t)(d >> 4) * 512 + ((((d >> 3) & 1) << 5) + tin) * 8 + (d & 7);
          else
            off = (size_t)(4 + ((d >> 5) << 1) + (tin >> 4)) * 512 +
                  ((((tin >> 3) & 1) << 5) + (d & 31)) * 8 + (tin & 7);
          outb[base + off] = f2bf(v);
        } else {
          size_t idx = (size_t)(rb + rr) * N + col;
          if constexpr (OM == 0) {
            outb[idx] = f2bf(v);
          } else if constexpr (OM == 1) {
            outb[idx] = f2bf(fmaf(rscale, v, bf2f(resid[idx])));
          } else {
            float sn = __sinf(sa * v);
            outb[idx] = f2bf(v + sn * sn * sib);
          }
        }
      }
    }
  }
}

// ---------------------------------------------------------------------------
// bf16 GEMM: acc = A bf16[M,K] @ B bf16[N,K]^T + bias. XCD swizzle.
// OM=1: bf16 out = bf16(resid) + acc + bias.  (out_proj only)
// ---------------------------------------------------------------------------
template <int BN, int OM>
__global__ __launch_bounds__(256) void gemm_bf16_t(
    const u16* __restrict__ A, const u16* __restrict__ B,
    const float* __restrict__ bias, const u16* __restrict__ resid,
    u16* __restrict__ outb, int N, int K) {
  constexpr int JF = BN / 32;
  __shared__ signed char As[8192];
  __shared__ signed char Bs[BN * 64];
  const int tid = threadIdx.x;
  int txc, tyc;
  xcd_tiles(txc, tyc);
  const int m0 = tyc << 7;
  const int n0 = txc * BN;
  const int lane = tid & 63;
  const int wv = tid >> 6;
  const int wr = (wv >> 1) << 6, wc = (wv & 1) * (16 * JF);
  const int r15 = lane & 15, khi = lane >> 4;
  const int srow = tid >> 2;
  const int sslot = (tid & 3) ^ ((srow >> 1) & 3);
  const int K2 = K * 2;
  const signed char* Ag = (const signed char*)A + (size_t)(m0 + srow) * K2 + sslot * 16;
  const signed char* Bg = (const signed char*)B + (size_t)(n0 + srow) * K2 + sslot * 16;
  const size_t half = (size_t)64 * K2;

  int aoff[4], boff[JF];
#pragma unroll
  for (int i = 0; i < 4; ++i) {
    int r = wr + i * 16 + r15;
    aoff[i] = r * 64 + ((khi ^ ((r >> 1) & 3)) << 4);
  }
#pragma unroll
  for (int j = 0; j < JF; ++j) {
    int c = wc + j * 16 + r15;
    boff[j] = c * 64 + ((khi ^ ((c >> 1) & 3)) << 4);
  }
  v4f acc[4][JF] = {};
  for (int kb = 0; kb < K2; kb += 64) {
    __syncthreads();
    GLOAD_LDS(Ag + kb, As + tid * 16);
    GLOAD_LDS(Ag + half + kb, As + 4096 + tid * 16);
    GLOAD_LDS(Bg + kb, Bs + tid * 16);
    if constexpr (BN == 128) GLOAD_LDS(Bg + half + kb, Bs + 4096 + tid * 16);
    __syncthreads();
    v8s a[4], b[JF];
#pragma unroll
    for (int i = 0; i < 4; ++i) a[i] = *(const v8s*)(As + aoff[i]);
#pragma unroll
    for (int j = 0; j < JF; ++j) b[j] = *(const v8s*)(Bs + boff[j]);
#pragma unroll
    for (int i = 0; i < 4; ++i)
#pragma unroll
      for (int j = 0; j < JF; ++j)
        acc[i][j] = __builtin_amdgcn_mfma_f32_16x16x32_bf16(a[i], b[j], acc[i][j], 0, 0, 0);
  }
#pragma unroll
  for (int i = 0; i < 4; ++i) {
    int rb = m0 + wr + i * 16 + (khi << 2);
#pragma unroll
    for (int j = 0; j < JF; ++j) {
      int col = n0 + wc + j * 16 + r15;
      float bv = bias[col];
#pragma unroll
      for (int rr = 0; rr < 4; ++rr) {
        size_t idx = (size_t)(rb + rr) * N + col;
        float v = acc[i][j][rr] + bv;
        if constexpr (OM == 0) outb[idx] = f2bf(v);
        else outb[idx] = f2bf(bf2f(resid[idx]) + v);
      }
    }
  }
}

// ---------------------------------------------------------------------------
// Flash attention, swapped-operand 32x32 bf16 MFMA, LDS-staged K/V (dbuf),
// max-free softmax with C-prescaled Q (p = exp2(sacc) directly), k-split x1,
// bh-affinity XCD remap. grid (16 qgroups, 32 bh) flat-remapped.
// ---------------------------------------------------------------------------
__global__ __launch_bounds__(256) void attn32(
    const u16* __restrict__ kvqp, u16* __restrict__ attno) {
  __shared__ u16 KV[2][4096];
  const int tid = threadIdx.x;
  const int lane = tid & 63;
  const int wv = tid >> 6;
  const int l31 = lane & 31;
  const int hi = lane >> 5;
  const int flat = blockIdx.y * 16 + blockIdx.x;
  const int qg = flat >> 5;
  const int bh = (flat & 7) | (((flat >> 3) & 3) << 3);
  const int b = bh >> 3, h = bh & 7;
  const int qt = qg * 4 + wv;
  const int q0 = qt << 5;

  v8s qf[4];
  {
    const u16* qb = kvqp + ((size_t)(bh * 64 + qt)) * 6144 + lane * 8;
#pragma unroll
    for (int ks = 0; ks < 4; ++ks) qf[ks] = *(const v8s*)(qb + (8 + ks) * 512);
  }
  v16f o0 = {}, o1 = {};
  float l_run = 0.f;

  const u16* tb = kvqp + ((size_t)(bh * 64)) * 6144;

  GLOAD_LDS(tb + tid * 8, &KV[0][tid * 8]);
  GLOAD_LDS(tb + 2048 + tid * 8, &KV[0][2048 + tid * 8]);
  __syncthreads();

  int cur = 0;
#pragma unroll 2
  for (int t = 0; t < 64; ++t) {
    if (t < 63) {
      const u16* nb = tb + (size_t)(t + 1) * 6144;
      GLOAD_LDS(nb + tid * 8, &KV[cur ^ 1][tid * 8]);
      GLOAD_LDS(nb + 2048 + tid * 8, &KV[cur ^ 1][2048 + tid * 8]);
    }
    v8s kf[4], vf[4];
#pragma unroll
    for (int ks = 0; ks < 4; ++ks) kf[ks] = *(const v8s*)(&KV[cur][ks * 512 + lane * 8]);
#pragma unroll
    for (int j = 0; j < 4; ++j) vf[j] = *(const v8s*)(&KV[cur][2048 + j * 512 + lane * 8]);

    __builtin_amdgcn_s_setprio(1);
    v16f sacc = {};
#pragma unroll
    for (int ks = 0; ks < 4; ++ks)
      sacc = __builtin_amdgcn_mfma_f32_32x32x16_bf16(kf[ks], qf[ks], sacc, 0, 0, 0);
    __builtin_amdgcn_s_setprio(0);

    // Q was pre-scaled by C: p = exp2(sacc) directly.
    float s[16];
#pragma unroll
    for (int r = 0; r < 16; ++r) s[r] = exp2f(sacc[r]);

    {
      float a0 = (s[0] + s[1]) + (s[2] + s[3]);
      float a1 = (s[4] + s[5]) + (s[6] + s[7]);
      float a2 = (s[8] + s[9]) + (s[10] + s[11]);
      float a3 = (s[12] + s[13]) + (s[14] + s[15]);
      float ls = (a0 + a1) + (a2 + a3);
      float tsw = ls;
      asm("v_permlane32_swap_b32 %0, %1" : "+v"(tsw), "+v"(ls));
      l_run += ls + tsw;
    }

    unsigned pk[8];
#pragma unroll
    for (int g = 0; g < 8; ++g) {
      unsigned u;
      asm("v_cvt_pk_bf16_f32 %0, %1, %2" : "=v"(u) : "v"(s[2 * g]), "v"(s[2 * g + 1]));
      pk[g] = u;
    }
    asm("v_permlane32_swap_b32 %0, %1" : "+v"(pk[2]), "+v"(pk[0]));
    asm("v_permlane32_swap_b32 %0, %1" : "+v"(pk[3]), "+v"(pk[1]));
    asm("v_permlane32_swap_b32 %0, %1" : "+v"(pk[6]), "+v"(pk[4]));
    asm("v_permlane32_swap_b32 %0, %1" : "+v"(pk[7]), "+v"(pk[5]));
    v4i w0, w1;
    w0[0] = pk[0]; w0[1] = pk[1]; w0[2] = pk[2]; w0[3] = pk[3];
    w1[0] = pk[4]; w1[1] = pk[5]; w1[2] = pk[6]; w1[3] = pk[7];
    v8s pf0 = *(v8s*)&w0;
    v8s pf1 = *(v8s*)&w1;

    __builtin_amdgcn_s_setprio(1);
    o0 = __builtin_amdgcn_mfma_f32_32x32x16_bf16(vf[0], pf0, o0, 0, 0, 0);
    o0 = __builtin_amdgcn_mfma_f32_32x32x16_bf16(vf[1], pf1, o0, 0, 0, 0);
    o1 = __builtin_amdgcn_mfma_f32_32x32x16_bf16(vf[2], pf0, o1, 0, 0, 0);
    o1 = __builtin_amdgcn_mfma_f32_32x32x16_bf16(vf[3], pf1, o1, 0, 0, 0);
    __builtin_amdgcn_s_setprio(0);

    __syncthreads();
    cur ^= 1;
  }

  float inv = 1.0f / l_run;
  u16* orow = attno + (size_t)(b * 2048 + q0 + l31) * 512 + h * 64;
#pragma unroll
  for (int dt = 0; dt < 2; ++dt) {
#pragma unroll
    for (int g = 0; g < 8; ++g) {
      int d = dt * 32 + ((2 * g) & 3) + 8 * (g >> 1) + 4 * hi;
      float a = (dt ? o1[2 * g] : o0[2 * g]) * inv;
      float bv = (dt ? o1[2 * g + 1] : o0[2 * g + 1]) * inv;
      unsigned u;
      asm("v_cvt_pk_bf16_f32 %0, %1, %2" : "=v"(u) : "v"(a), "v"(bv));
      *(unsigned*)(orow + d) = u;
    }
  }
}

// ---------------------------------------------------------------------------
// Fused GLU + depthwise conv(K=31) + BN + snake. In: g3 bf16 [8192,1024].
// Out: bf16 [8192,512]. Block: (chgroup 64, t-tile 128, batch).
// ---------------------------------------------------------------------------
__global__ __launch_bounds__(256) void dwconv_fused(
    const u16* __restrict__ g3, const float* __restrict__ dww,
    const float* __restrict__ dwb, const float* __restrict__ bng,
    const float* __restrict__ bnb, const float* __restrict__ bnm,
    const float* __restrict__ bnv, const float* __restrict__ la,
    const float* __restrict__ lb, u16* __restrict__ outp) {
  __shared__ float IN[160 * 64];
  __shared__ float WT[1984];
  __shared__ float PRM[4][64];
  const int tid = threadIdx.x;
  const int cg = blockIdx.x << 6;
  const int t0 = blockIdx.y << 7;
  const int bb = blockIdx.z;

  if (tid < 64) {
    int c = cg + tid;
    float sc = bng[c] / sqrtf(bnv[c] + 1e-5f);
    PRM[0][tid] = sc;
    PRM[1][tid] = (dwb[c] - bnm[c]) * sc + bnb[c];
    PRM[2][tid] = __expf(la[c]);
    PRM[3][tid] = 1.0f / (__expf(lb[c]) + 1e-9f);
  }
  for (int i = tid; i < 1984; i += 256) WT[i] = dww[cg * 31 + i];

#pragma unroll
  for (int p = 0; p < 5; ++p) {
    int r = p * 32 + (tid >> 3);
    int t = t0 - 16 + r;
    int c8 = (tid & 7) << 3;
    float4 lo = make_float4(0.f, 0.f, 0.f, 0.f);
    float4 hv = make_float4(0.f, 0.f, 0.f, 0.f);
    if (t >= 0 && t < 2048) {
      const u16* rp = g3 + ((size_t)(bb * 2048 + t)) * 1024 + cg + c8;
      v8s a8 = *(const v8s*)rp;
      v8s g8 = *(const v8s*)(rp + 512);
      float va[8];
#pragma unroll
      for (int j = 0; j < 8; ++j) {
        float fa = bf2f((u16)a8[j]);
        float fg = bf2f((u16)g8[j]);
        va[j] = fa / (1.f + __expf(-fg));
      }
      lo = make_float4(va[0], va[1], va[2], va[3]);
      hv = make_float4(va[4], va[5], va[6], va[7]);
    }
    *(float4*)&IN[r * 64 + c8] = lo;
    *(float4*)&IN[r * 64 + c8 + 4] = hv;
  }
  __syncthreads();

  const int ch = tid & 63;
  const int tg = tid >> 6;
  const float sc = PRM[0][ch], sh = PRM[1][ch], sa = PRM[2][ch], sib = PRM[3][ch];
  float w[31];
#pragma unroll
  for (int k = 0; k < 31; ++k) w[k] = WT[ch * 31 + k];

  for (int pass = 0; pass < 4; ++pass) {
    int tl = pass * 32 + tg * 8;
    float x[38];
#pragma unroll
    for (int i = 0; i < 38; ++i) x[i] = IN[(tl + 1 + i) * 64 + ch];
    float acc[8] = {0.f, 0.f, 0.f, 0.f, 0.f, 0.f, 0.f, 0.f};
#pragma unroll
    for (int k = 0; k < 31; ++k)
#pragma unroll
      for (int j = 0; j < 8; ++j) acc[j] = fmaf(x[k + j], w[k], acc[j]);
#pragma unroll
    for (int j = 0; j < 8; ++j) {
      float v = acc[j] * sc + sh;
      float s = __sinf(sa * v);
      v += s * s * sib;
      outp[((size_t)(bb * 2048 + t0 + tl + j)) * 512 + cg + ch] = f2bf(v);
    }
  }
}

// ---------------------------------------------------------------------------
extern "C" void kernel_launch(void* const* d_in, const int* in_sizes, int n_in,
                              void* d_out, int out_size, void* d_ws, size_t ws_size,
                              hipStream_t stream) {
  const float* x_in = (const float*)d_in[0];
  const float* ff1_norm_w = (const float*)d_in[1];
  const float* ff1_w1 = (const float*)d_in[2];
  const float* ff1_a = (const float*)d_in[3];
  const float* ff1_b = (const float*)d_in[4];
  const float* ff1_w2 = (const float*)d_in[5];
  const float* attn_norm_w = (const float*)d_in[6];
  const float* in_proj_w = (const float*)d_in[7];
  const float* in_proj_b = (const float*)d_in[8];
  const float* out_proj_w = (const float*)d_in[9];
  const float* out_proj_b = (const float*)d_in[10];
  const float* conv_norm_w = (const float*)d_in[11];
  const float* pw1_w = (const float*)d_in[12];
  const float* dw_w = (const float*)d_in[13];
  const float* dw_b = (const float*)d_in[14];
  const float* bn_g = (const float*)d_in[15];
  const float* bn_b = (const float*)d_in[16];
  const float* bn_m = (const float*)d_in[17];
  const float* bn_v = (const float*)d_in[18];
  const float* snake_a = (const float*)d_in[19];
  const float* snake_b = (const float*)d_in[20];
  const float* pw2_w = (const float*)d_in[21];
  const float* ff2_norm_w = (const float*)d_in[22];
  const float* ff2_w1 = (const float*)d_in[23];
  const float* ff2_a = (const float*)d_in[24];
  const float* ff2_b = (const float*)d_in[25];
  const float* ff2_w2 = (const float*)d_in[26];
  const float* final_norm_w = (const float*)d_in[27];
  float* out = (float*)d_out;

  char* ws = (char*)d_ws;
  u16* x_bf = (u16*)(ws + 0);                          // 8 MiB  (bf16 of x_in)
  u16* x_cur = (u16*)(ws + 8388608);                   // 8 MiB  (bf16 residual)
  // attn phase:
  u16* kvqp = (u16*)(ws + 41943040);                   // 24 MiB (packed Q/K/V)
  u16* attno = (u16*)(ws + 100663296);                 // 8 MiB
  // FFN phase:
  u16* h_b = (u16*)(ws + 16777216);                    // 32 MiB
  // conv phase:
  u16* g3b = (u16*)(ws + 16777216);                    // 16 MiB
  u16* convout = (u16*)(ws + 50331648);                // 8 MiB
  signed char* a8a = (signed char*)(ws + 83886080);    // 4 MiB
  signed char* a8b = (signed char*)(ws + 88080384);    // 16 MiB
  signed char* wq = (signed char*)(ws + 113246208);    // ternary 4.75 MiB + in_proj i8
  signed char* wq_w1 = wq;
  signed char* wq_w2 = wq + 1048576;
  signed char* wq_p1 = wq + 2097152;
  signed char* wq_p2 = wq + 2621440;
  signed char* wq_f21 = wq + 2883584;
  signed char* wq_f22 = wq + 3932160;
  signed char* wq_ip = wq + 4980736;                   // 786432 B (int8 in_proj)
  u16* wb = (u16*)(ws + 119013376);                    // 512 KiB (bf16 out_proj)
  u16* wb_op = wb;
  float* scales = (float*)(ws + 120324096);            // 7 floats
  float* partials = (float*)(ws + 120324352);          // 7*64 floats
  float* ascale = (float*)(ws + 120325888);            // 32 KiB
  float* tabs = (float*)(ws + 120358912);              // 32 KiB

  // --- weight prep ---
  wabs_stage1<<<448, 256, 0, stream>>>(ff1_w1, ff1_w2, pw1_w, pw2_w, ff2_w1, ff2_w2,
                                       in_proj_w, partials);
  wquant_all<<<dim3(128, 7), 256, 0, stream>>>(ff1_w1, ff1_w2, pw1_w, pw2_w, ff2_w1, ff2_w2,
                                               in_proj_w, partials, scales, wq);
  wcvt_tabs<<<264, 256, 0, stream>>>(out_proj_w, wb, ff1_a, ff1_b, ff2_a, ff2_b, tabs);

  // --- FFN1: x_cur = x + 0.5*ffn(x)  (snake fused into up-GEMM epilogue) ---
  rmsnorm_f32x<<<2048, 256, 0, stream>>>(x_in, ff1_norm_w, a8a, x_bf, ascale);
  gemm_i8_t<128, 2><<<dim3(16, 64), 256, 0, stream>>>(
      a8a, wq_w1, scales + 0, ascale, nullptr, 1.0f, h_b, 2048, 512, tabs, tabs + 2048, nullptr);
  rq2048_wave<<<2048, 256, 0, stream>>>(h_b, a8b, ascale);
  gemm_i8_t<64, 1><<<dim3(8, 64), 256, 0, stream>>>(
      a8b, wq_w2, scales + 1, ascale, x_bf, 0.5f, x_cur, 512, 2048, nullptr, nullptr, nullptr);

  // --- MHA: x_cur += mha(x_cur)  (int8 in_proj scatters packed kvqp) ---
  rmsnorm_wave<<<2048, 256, 0, stream>>>(x_cur, attn_norm_w, 1, nullptr, a8a, nullptr, ascale);
  gemm_i8_t<128, 3><<<dim3(12, 64), 256, 0, stream>>>(
      a8a, wq_ip, scales + 6, ascale, nullptr, 1.0f, kvqp, 1536, 512, nullptr, nullptr,
      in_proj_b);
  attn32<<<dim3(16, 32), 256, 0, stream>>>(kvqp, attno);
  gemm_bf16_t<64, 1><<<dim3(8, 64), 256, 0, stream>>>(
      attno, wb_op, out_proj_b, x_cur, x_cur, 512, 512);

  // --- conv branch: x_cur += conv(x_cur) ---
  rmsnorm_wave<<<2048, 256, 0, stream>>>(x_cur, conv_norm_w, 1, nullptr, a8a, nullptr, ascale);
  gemm_i8_t<128, 0><<<dim3(8, 64), 256, 0, stream>>>(
      a8a, wq_p1, scales + 2, ascale, nullptr, 1.0f, g3b, 1024, 512, nullptr, nullptr, nullptr);
  dwconv_fused<<<dim3(8, 16, 4), 256, 0, stream>>>(g3b, dw_w, dw_b, bn_g, bn_b, bn_m, bn_v,
                                                   snake_a, snake_b, convout);
  rowquant_wave<<<2048, 256, 0, stream>>>(convout, a8a, ascale);
  gemm_i8_t<64, 1><<<dim3(8, 64), 256, 0, stream>>>(
      a8a, wq_p2, scales + 3, ascale, x_cur, 1.0f, x_cur, 512, 512, nullptr, nullptr, nullptr);

  // --- FFN2: x_cur += 0.5*ffn(x_cur) ---
  rmsnorm_wave<<<2048, 256, 0, stream>>>(x_cur, ff2_norm_w, 1, nullptr, a8a, nullptr, ascale);
  gemm_i8_t<128, 2><<<dim3(16, 64), 256, 0, stream>>>(
      a8a, wq_f21, scales + 4, ascale, nullptr, 1.0f, h_b, 2048, 512, tabs + 4096, tabs + 6144,
      nullptr);
  rq2048_wave<<<2048, 256, 0, stream>>>(h_b, a8b, ascale);
  gemm_i8_t<64, 1><<<dim3(8, 64), 256, 0, stream>>>(
      a8b, wq_f22, scales + 5, ascale, x_cur, 0.5f, x_cur, 512, 2048, nullptr, nullptr, nullptr);

  // --- final rmsnorm -> out (f32) ---
  rmsnorm_wave<<<2048, 256, 0, stream>>>(x_cur, final_norm_w, 0, out, nullptr, nullptr, nullptr);
}

// Round 22
// 280.019 us; speedup vs baseline: 1.0453x; 1.0362x over previous
//
#include <hip/hip_runtime.h>
#include <math.h>

// ---------------------------------------------------------------------------
// ConformerBlock MFMA implementation.
// B=4, T=2048, D=512, H=8, hd=64, K=31.  M = B*T = 8192.
// Bitlinear GEMMs + in_proj: int8 MFMA (BK=128, XCD-swizzled; BM templated,
// 64x64 tiles for the occupancy-starved N=512 GEMMs). bf16 residual stream.
// Attention: swapped-operand 32x32 MFMA, LDS-staged K/V (dbuf), max-free
// softmax with C-prescaled Q and l computed via ones-MFMA on the matrix pipe,
// k-split x1, bh-affinity XCD remap. in_proj scatters packed kvqp; FFN-up
// applies snake in epilogue.
// ---------------------------------------------------------------------------

typedef int   v4i __attribute__((ext_vector_type(4)));
typedef float v4f __attribute__((ext_vector_type(4)));
typedef float v16f __attribute__((ext_vector_type(16)));
typedef short v8s __attribute__((ext_vector_type(8)));
typedef unsigned short u16;

#define GLOAD_LDS(g, l) __builtin_amdgcn_global_load_lds( \
    (const __attribute__((address_space(1))) void*)(g),   \
    (__attribute__((address_space(3))) void*)(l), 16, 0, 0)

__device__ __forceinline__ float blk_sum256(float v, float* sm) {
#pragma unroll
  for (int m = 32; m; m >>= 1) v += __shfl_xor(v, m);
  int w = threadIdx.x >> 6;
  __syncthreads();
  if ((threadIdx.x & 63) == 0) sm[w] = v;
  __syncthreads();
  return sm[0] + sm[1] + sm[2] + sm[3];
}

__device__ __forceinline__ float blk_max256(float v, float* sm) {
#pragma unroll
  for (int m = 32; m; m >>= 1) v = fmaxf(v, __shfl_xor(v, m));
  int w = threadIdx.x >> 6;
  __syncthreads();
  if ((threadIdx.x & 63) == 0) sm[w] = v;
  __syncthreads();
  return fmaxf(fmaxf(sm[0], sm[1]), fmaxf(sm[2], sm[3]));
}

__device__ __forceinline__ u16 f2bf(float f) {
  union { float f; unsigned u; } x;
  x.f = f;
  unsigned r = x.u + 0x7fffu + ((x.u >> 16) & 1u);
  return (u16)(r >> 16);
}

__device__ __forceinline__ float bf2f(u16 u) {
  union { unsigned u; float f; } x;
  x.u = ((unsigned)u) << 16;
  return x.f;
}

// XCD-aware bijective block remap (nwg divisible by 8 for all our grids).
__device__ __forceinline__ void xcd_tiles(int& tx, int& ty) {
  int nx = gridDim.x;
  int flat = blockIdx.y * nx + blockIdx.x;
  int nwg = nx * gridDim.y;
  int cpx = nwg >> 3;
  int swz = (flat & 7) * cpx + (flat >> 3);
  ty = swz / nx;
  tx = swz - ty * nx;
}

// ---------------------------------------------------------------------------
// Weight reductions: widx 0..5 ternary (sum|w| -> mean), widx 6 in_proj
// (max|w| for int8 quant). grid = 7*64.
// ---------------------------------------------------------------------------
__global__ __launch_bounds__(256) void wabs_stage1(
    const float* __restrict__ w0, const float* __restrict__ w1,
    const float* __restrict__ w2, const float* __restrict__ w3,
    const float* __restrict__ w4, const float* __restrict__ w5,
    const float* __restrict__ w6, float* __restrict__ part) {
  __shared__ float sm[4];
  const float* ws[7] = {w0, w1, w2, w3, w4, w5, w6};
  const int ns[7] = {1048576, 1048576, 524288, 262144, 1048576, 1048576, 786432};
  int widx = blockIdx.x >> 6;
  int chunk = blockIdx.x & 63;
  const float* w = ws[widx];
  int n = ns[widx];
  if (widx < 6) {
    float s = 0.f;
    for (int i = chunk * 256 + threadIdx.x; i < n; i += 64 * 256) s += fabsf(w[i]);
    s = blk_sum256(s, sm);
    if (threadIdx.x == 0) part[widx * 64 + chunk] = s;
  } else {
    float s = 0.f;
    for (int i = chunk * 256 + threadIdx.x; i < n; i += 64 * 256) s = fmaxf(s, fabsf(w[i]));
    s = blk_max256(s, sm);
    if (threadIdx.x == 0) part[widx * 64 + chunk] = s;
  }
}

// stage2 folded in: every block recomputes the 64-partial reduce for its widx.
__global__ __launch_bounds__(256) void wquant_all(
    const float* __restrict__ w0, const float* __restrict__ w1,
    const float* __restrict__ w2, const float* __restrict__ w3,
    const float* __restrict__ w4, const float* __restrict__ w5,
    const float* __restrict__ w6,
    const float* __restrict__ part, float* __restrict__ scales,
    signed char* __restrict__ out) {
  const float* ws[7] = {w0, w1, w2, w3, w4, w5, w6};
  const int ns[7] = {1048576, 1048576, 524288, 262144, 1048576, 1048576, 786432};
  const int offs[7] = {0, 1048576, 2097152, 2621440, 2883584, 3932160, 4980736};
  int widx = blockIdx.y;
  const float* w = ws[widx];
  int n = ns[widx];
  signed char* o = out + offs[widx];
  float s, clipv;
  if (widx < 6) {
    float ssum = 0.f;
#pragma unroll 8
    for (int i = 0; i < 64; ++i) ssum += part[widx * 64 + i];
    float wsc = fmaxf(ssum / (float)n, 1e-5f);
    if (blockIdx.x == 0 && threadIdx.x == 0) scales[widx] = wsc;
    s = 1.0f / wsc;
    clipv = 1.f;
  } else {
    float am = 0.f;
#pragma unroll 8
    for (int i = 0; i < 64; ++i) am = fmaxf(am, part[widx * 64 + i]);
    float step = fmaxf(am, 1e-5f) * (1.0f / 127.0f);
    if (blockIdx.x == 0 && threadIdx.x == 0) scales[widx] = step;
    s = 1.0f / step;
    clipv = 127.f;
  }
  for (int i = blockIdx.x * 256 + threadIdx.x; i < n; i += 128 * 256)
    o[i] = (signed char)(int)fminf(fmaxf(rintf(w[i] * s), -clipv), clipv);
}

// bf16 out_proj convert (x4 vectorized) + snake exp tables in one launch.
__global__ __launch_bounds__(256) void wcvt_tabs(
    const float* __restrict__ op, u16* __restrict__ wb,
    const float* __restrict__ a1, const float* __restrict__ b1,
    const float* __restrict__ a2, const float* __restrict__ b2,
    float* __restrict__ tabs) {
  int bid = blockIdx.x;
  if (bid < 256) {
    int i = bid * 256 + threadIdx.x;
    float4 f = *(const float4*)(op + (size_t)i * 4);
    u16* dst = wb + (size_t)i * 4;
    dst[0] = f2bf(f.x); dst[1] = f2bf(f.y); dst[2] = f2bf(f.z); dst[3] = f2bf(f.w);
  } else {
    int i = (bid - 256) * 256 + threadIdx.x;
    if (i < 2048) {
      tabs[i] = __expf(a1[i]);
      tabs[2048 + i] = 1.0f / (__expf(b1[i]) + 1e-9f);
      tabs[4096 + i] = __expf(a2[i]);
      tabs[6144 + i] = 1.0f / (__expf(b2[i]) + 1e-9f);
    }
  }
}

// ---------------------------------------------------------------------------
// Wave-per-row RMSNorm over f32 rows of 512 (4 rows/block): emits bf16 copy
// of x AND int8 quant + dq.
// ---------------------------------------------------------------------------
__global__ __launch_bounds__(256) void rmsnorm_f32x(
    const float* __restrict__ x, const float* __restrict__ w,
    signed char* __restrict__ out8, u16* __restrict__ xbf,
    float* __restrict__ dq) {
  const int tid = threadIdx.x;
  const int lane = tid & 63, wv = tid >> 6;
  const int row = blockIdx.x * 4 + wv;
  const int c0 = lane * 8;
  const float* xr = x + (size_t)row * 512 + c0;
  float4 f0 = *(const float4*)xr;
  float4 f1 = *(const float4*)(xr + 4);
  float fin[8] = {f0.x, f0.y, f0.z, f0.w, f1.x, f1.y, f1.z, f1.w};
  v8s xb;
  float v[8];
  float ss = 0.f;
#pragma unroll
  for (int j = 0; j < 8; ++j) {
    u16 b = f2bf(fin[j]);
    xb[j] = (short)b;
    v[j] = bf2f(b);
    ss = fmaf(v[j], v[j], ss);
  }
  *(v8s*)(xbf + (size_t)row * 512 + c0) = xb;
#pragma unroll
  for (int m = 1; m < 64; m <<= 1) ss += __shfl_xor(ss, m);
  float sc = 1.0f / sqrtf(ss * (1.0f / 512.0f) + 1e-6f);
  float4 w0 = *(const float4*)(w + c0);
  float4 w1 = *(const float4*)(w + c0 + 4);
  float wv8[8] = {w0.x, w0.y, w0.z, w0.w, w1.x, w1.y, w1.z, w1.w};
  float y[8];
  float am = 0.f;
#pragma unroll
  for (int j = 0; j < 8; ++j) {
    y[j] = v[j] * sc * wv8[j];
    am = fmaxf(am, fabsf(y[j]));
  }
#pragma unroll
  for (int m = 1; m < 64; m <<= 1) am = fmaxf(am, __shfl_xor(am, m));
  float amc = fmaxf(am, 1e-5f);
  float s = 127.0f / amc;
  unsigned long long pkt = 0;
#pragma unroll
  for (int j = 0; j < 8; ++j) {
    int q = (int)rintf(y[j] * s);
    pkt |= ((unsigned long long)(unsigned char)(signed char)q) << (8 * j);
  }
  *(unsigned long long*)(out8 + (size_t)row * 512 + c0) = pkt;
  if (lane == 0) dq[row] = amc * (1.0f / 127.0f);
}

// ---------------------------------------------------------------------------
// Wave-per-row RMSNorm over bf16 rows of 512 (4 rows/block).
// mode 0: f32 out.  mode 1: int8-quant out + dq.  mode 2: bf16 out.
// ---------------------------------------------------------------------------
__global__ __launch_bounds__(256) void rmsnorm_wave(
    const u16* __restrict__ x, const float* __restrict__ w, int mode,
    float* __restrict__ outf, signed char* __restrict__ out8,
    u16* __restrict__ outb, float* __restrict__ dq) {
  const int tid = threadIdx.x;
  const int lane = tid & 63, wv = tid >> 6;
  const int row = blockIdx.x * 4 + wv;
  const int c0 = lane * 8;
  v8s xv = *(const v8s*)(x + (size_t)row * 512 + c0);
  float v[8];
  float ss = 0.f;
#pragma unroll
  for (int j = 0; j < 8; ++j) {
    v[j] = bf2f((u16)xv[j]);
    ss = fmaf(v[j], v[j], ss);
  }
#pragma unroll
  for (int m = 1; m < 64; m <<= 1) ss += __shfl_xor(ss, m);
  float sc = 1.0f / sqrtf(ss * (1.0f / 512.0f) + 1e-6f);
  float4 w0 = *(const float4*)(w + c0);
  float4 w1 = *(const float4*)(w + c0 + 4);
  float wv8[8] = {w0.x, w0.y, w0.z, w0.w, w1.x, w1.y, w1.z, w1.w};
  float y[8];
#pragma unroll
  for (int j = 0; j < 8; ++j) y[j] = v[j] * sc * wv8[j];
  if (mode == 0) {
    float* o = outf + (size_t)row * 512 + c0;
    *(float4*)o = make_float4(y[0], y[1], y[2], y[3]);
    *(float4*)(o + 4) = make_float4(y[4], y[5], y[6], y[7]);
  } else if (mode == 1) {
    float am = 0.f;
#pragma unroll
    for (int j = 0; j < 8; ++j) am = fmaxf(am, fabsf(y[j]));
#pragma unroll
    for (int m = 1; m < 64; m <<= 1) am = fmaxf(am, __shfl_xor(am, m));
    float amc = fmaxf(am, 1e-5f);
    float s = 127.0f / amc;
    unsigned long long pkt = 0;
#pragma unroll
    for (int j = 0; j < 8; ++j) {
      int q = (int)rintf(y[j] * s);
      pkt |= ((unsigned long long)(unsigned char)(signed char)q) << (8 * j);
    }
    *(unsigned long long*)(out8 + (size_t)row * 512 + c0) = pkt;
    if (lane == 0) dq[row] = amc * (1.0f / 127.0f);
  } else {
    v8s o;
#pragma unroll
    for (int j = 0; j < 8; ++j) o[j] = (short)f2bf(y[j]);
    *(v8s*)(outb + (size_t)row * 512 + c0) = o;
  }
}

// ---------------------------------------------------------------------------
// Wave-per-row int8 quant over bf16 rows of 2048 (32 elems/lane, 4 rows/blk).
// ---------------------------------------------------------------------------
__global__ __launch_bounds__(256) void rq2048_wave(
    const u16* __restrict__ h, signed char* __restrict__ out, float* __restrict__ dq) {
  const int tid = threadIdx.x;
  const int lane = tid & 63, wv = tid >> 6;
  const int row = blockIdx.x * 4 + wv;
  const u16* hr = h + (size_t)row * 2048;
  float vals[32];
  float am = 0.f;
#pragma unroll
  for (int g = 0; g < 4; ++g) {
    int c0 = g * 512 + lane * 8;
    v8s hv = *(const v8s*)(hr + c0);
#pragma unroll
    for (int j = 0; j < 8; ++j) {
      float v = bf2f((u16)hv[j]);
      vals[g * 8 + j] = v;
      am = fmaxf(am, fabsf(v));
    }
  }
#pragma unroll
  for (int m = 1; m < 64; m <<= 1) am = fmaxf(am, __shfl_xor(am, m));
  float amc = fmaxf(am, 1e-5f);
  float s = 127.0f / amc;
#pragma unroll
  for (int g = 0; g < 4; ++g) {
    unsigned long long pkt = 0;
#pragma unroll
    for (int j = 0; j < 8; ++j) {
      int q = (int)rintf(vals[g * 8 + j] * s);
      pkt |= ((unsigned long long)(unsigned char)(signed char)q) << (8 * j);
    }
    *(unsigned long long*)(out + (size_t)row * 2048 + g * 512 + lane * 8) = pkt;
  }
  if (lane == 0) dq[row] = amc * (1.0f / 127.0f);
}

// ---------------------------------------------------------------------------
// Wave-per-row int8 quant of [M,512] bf16 (4 rows/block).
// ---------------------------------------------------------------------------
__global__ __launch_bounds__(256) void rowquant_wave(
    const u16* __restrict__ in, signed char* __restrict__ out, float* __restrict__ dq) {
  const int tid = threadIdx.x;
  const int lane = tid & 63, wv = tid >> 6;
  const int row = blockIdx.x * 4 + wv;
  const int c0 = lane * 8;
  v8s xv = *(const v8s*)(in + (size_t)row * 512 + c0);
  float v[8];
  float am = 0.f;
#pragma unroll
  for (int j = 0; j < 8; ++j) {
    v[j] = bf2f((u16)xv[j]);
    am = fmaxf(am, fabsf(v[j]));
  }
#pragma unroll
  for (int m = 1; m < 64; m <<= 1) am = fmaxf(am, __shfl_xor(am, m));
  float amc = fmaxf(am, 1e-5f);
  float s = 127.0f / amc;
  unsigned long long pkt = 0;
#pragma unroll
  for (int j = 0; j < 8; ++j) {
    int q = (int)rintf(v[j] * s);
    pkt |= ((unsigned long long)(unsigned char)(signed char)q) << (8 * j);
  }
  *(unsigned long long*)(out + (size_t)row * 512 + c0) = pkt;
  if (lane == 0) dq[row] = amc * (1.0f / 127.0f);
}

// ---------------------------------------------------------------------------
// int8 GEMM: acc = (A i8[M,K] @ B i8[N,K]^T) * wsc * dq[m].
// BMxBN tile, BK=128, XCD swizzle. BM in {64,128}: 64 doubles the grid for
// the occupancy-starved N=512 GEMMs (4 blocks/CU vs 2).
// OM=0: bf16 out. OM=1: bf16 out = bf16(resid) + rscale*acc.
// OM=2: bf16 out = snake(acc) via tables ta/tb (FFN-up, N=2048).
// OM=3: acc + bias, scatter into fragment-packed kvqp (in_proj, N=1536);
//       Q segment is pre-scaled by C = 0.125*log2(e) for max-free softmax.
// ---------------------------------------------------------------------------
template <int BM, int BN, int OM>
__global__ __launch_bounds__(256) void gemm_i8_t(
    const signed char* __restrict__ A, const signed char* __restrict__ B,
    const float* __restrict__ wsp, const float* __restrict__ adq,
    const u16* __restrict__ resid, float rscale,
    u16* __restrict__ outb, int N, int K,
    const float* __restrict__ ta, const float* __restrict__ tb,
    const float* __restrict__ bias) {
  constexpr int AI = BM / 32;   // A row-frags per wave (wave covers BM/2 rows)
  constexpr int JF = BN / 32;
  __shared__ signed char As[BM * 128];
  __shared__ signed char Bs[BN * 128];
  const int tid = threadIdx.x;
  int txc, tyc;
  xcd_tiles(txc, tyc);
  const int m0 = tyc * BM;
  const int n0 = txc * BN;
  const int lane = tid & 63;
  const int wv = tid >> 6;
  const int wr = (wv >> 1) * (BM / 2), wc = (wv & 1) * (16 * JF);
  const int r15 = lane & 15, khi = lane >> 4;
  const int srow = tid >> 3;
  const int sslot = (tid & 7) ^ (srow & 7);
  const signed char* Ag = A + (size_t)(m0 + srow) * K + sslot * 16;
  const signed char* Bg = B + (size_t)(n0 + srow) * K + sslot * 16;
  const size_t row32 = (size_t)32 * K;

  int aoff[AI][2], boff[JF][2];
#pragma unroll
  for (int i = 0; i < AI; ++i) {
    int r = wr + i * 16 + r15;
#pragma unroll
    for (int s = 0; s < 2; ++s)
      aoff[i][s] = r * 128 + (((s << 2) + khi) ^ (r & 7)) * 16;
  }
#pragma unroll
  for (int j = 0; j < JF; ++j) {
    int c = wc + j * 16 + r15;
#pragma unroll
    for (int s = 0; s < 2; ++s)
      boff[j][s] = c * 128 + (((s << 2) + khi) ^ (c & 7)) * 16;
  }
  v4i acc[AI][JF] = {};
  for (int k0 = 0; k0 < K; k0 += 128) {
    __syncthreads();
#pragma unroll
    for (int c = 0; c < BM / 32; ++c)
      GLOAD_LDS(Ag + c * row32 + k0, As + c * 4096 + tid * 16);
#pragma unroll
    for (int c = 0; c < BN / 32; ++c)
      GLOAD_LDS(Bg + c * row32 + k0, Bs + c * 4096 + tid * 16);
    __syncthreads();
    v4i a[AI][2], b[JF][2];
#pragma unroll
    for (int i = 0; i < AI; ++i) {
      a[i][0] = *(const v4i*)(As + aoff[i][0]);
      a[i][1] = *(const v4i*)(As + aoff[i][1]);
    }
#pragma unroll
    for (int j = 0; j < JF; ++j) {
      b[j][0] = *(const v4i*)(Bs + boff[j][0]);
      b[j][1] = *(const v4i*)(Bs + boff[j][1]);
    }
#pragma unroll
    for (int i = 0; i < AI; ++i)
#pragma unroll
      for (int j = 0; j < JF; ++j) {
        acc[i][j] = __builtin_amdgcn_mfma_i32_16x16x64_i8(a[i][0], b[j][0], acc[i][j], 0, 0, 0);
        acc[i][j] = __builtin_amdgcn_mfma_i32_16x16x64_i8(a[i][1], b[j][1], acc[i][j], 0, 0, 0);
      }
  }
  const float wsc = *wsp;
#pragma unroll
  for (int i = 0; i < AI; ++i) {
    int rb = m0 + wr + i * 16 + (khi << 2);
    float dqv[4];
#pragma unroll
    for (int rr = 0; rr < 4; ++rr) dqv[rr] = adq[rb + rr] * wsc;
#pragma unroll
    for (int j = 0; j < JF; ++j) {
      int col = n0 + wc + j * 16 + r15;
      float sa, sib, bv;
      if constexpr (OM == 2) { sa = ta[col]; sib = tb[col]; }
      if constexpr (OM == 3) { bv = bias[col]; }
#pragma unroll
      for (int rr = 0; rr < 4; ++rr) {
        float v = (float)acc[i][j][rr] * dqv[rr];
        if constexpr (OM == 3) {
          v += bv;
          int rowb = rb + rr;
          int tin = rowb & 31;
          int seg = col >> 9;           // 0=Q, 1=K, 2=V
          int cc = col & 511;
          int h2 = cc >> 6, d = cc & 63;
          if (seg == 0) v *= 0.18033688011112042f;  // fold 0.125*log2(e) into Q
          size_t base = ((size_t)(((rowb >> 11) * 8 + h2) * 64 + ((rowb & 2047) >> 5))) * 6144;
          size_t off;
          if (seg == 0)
            off = (size_t)(8 + (d >> 4)) * 512 + ((((d >> 3) & 1) << 5) + tin) * 8 + (d & 7);
          else if (seg == 1)
            off = (size_t)(d >> 4) * 512 + ((((d >> 3) & 1) << 5) + tin) * 8 + (d & 7);
          else
            off = (size_t)(4 + ((d >> 5) << 1) + (tin >> 4)) * 512 +
                  ((((tin >> 3) & 1) << 5) + (d & 31)) * 8 + (tin & 7);
          outb[base + off] = f2bf(v);
        } else {
          size_t idx = (size_t)(rb + rr) * N + col;
          if constexpr (OM == 0) {
            outb[idx] = f2bf(v);
          } else if constexpr (OM == 1) {
            outb[idx] = f2bf(fmaf(rscale, v, bf2f(resid[idx])));
          } else {
            float sn = __sinf(sa * v);
            outb[idx] = f2bf(v + sn * sn * sib);
          }
        }
      }
    }
  }
}

// ---------------------------------------------------------------------------
// bf16 GEMM: acc = A bf16[M,K] @ B bf16[N,K]^T + bias. XCD swizzle.
// OM=1: bf16 out = bf16(resid) + acc + bias.  (out_proj only)
// ---------------------------------------------------------------------------
template <int BN, int OM>
__global__ __launch_bounds__(256) void gemm_bf16_t(
    const u16* __restrict__ A, const u16* __restrict__ B,
    const float* __restrict__ bias, const u16* __restrict__ resid,
    u16* __restrict__ outb, int N, int K) {
  constexpr int JF = BN / 32;
  __shared__ signed char As[8192];
  __shared__ signed char Bs[BN * 64];
  const int tid = threadIdx.x;
  int txc, tyc;
  xcd_tiles(txc, tyc);
  const int m0 = tyc << 7;
  const int n0 = txc * BN;
  const int lane = tid & 63;
  const int wv = tid >> 6;
  const int wr = (wv >> 1) << 6, wc = (wv & 1) * (16 * JF);
  const int r15 = lane & 15, khi = lane >> 4;
  const int srow = tid >> 2;
  const int sslot = (tid & 3) ^ ((srow >> 1) & 3);
  const int K2 = K * 2;
  const signed char* Ag = (const signed char*)A + (size_t)(m0 + srow) * K2 + sslot * 16;
  const signed char* Bg = (const signed char*)B + (size_t)(n0 + srow) * K2 + sslot * 16;
  const size_t half = (size_t)64 * K2;

  int aoff[4], boff[JF];
#pragma unroll
  for (int i = 0; i < 4; ++i) {
    int r = wr + i * 16 + r15;
    aoff[i] = r * 64 + ((khi ^ ((r >> 1) & 3)) << 4);
  }
#pragma unroll
  for (int j = 0; j < JF; ++j) {
    int c = wc + j * 16 + r15;
    boff[j] = c * 64 + ((khi ^ ((c >> 1) & 3)) << 4);
  }
  v4f acc[4][JF] = {};
  for (int kb = 0; kb < K2; kb += 64) {
    __syncthreads();
    GLOAD_LDS(Ag + kb, As + tid * 16);
    GLOAD_LDS(Ag + half + kb, As + 4096 + tid * 16);
    GLOAD_LDS(Bg + kb, Bs + tid * 16);
    if constexpr (BN == 128) GLOAD_LDS(Bg + half + kb, Bs + 4096 + tid * 16);
    __syncthreads();
    v8s a[4], b[JF];
#pragma unroll
    for (int i = 0; i < 4; ++i) a[i] = *(const v8s*)(As + aoff[i]);
#pragma unroll
    for (int j = 0; j < JF; ++j) b[j] = *(const v8s*)(Bs + boff[j]);
#pragma unroll
    for (int i = 0; i < 4; ++i)
#pragma unroll
      for (int j = 0; j < JF; ++j)
        acc[i][j] = __builtin_amdgcn_mfma_f32_16x16x32_bf16(a[i], b[j], acc[i][j], 0, 0, 0);
  }
#pragma unroll
  for (int i = 0; i < 4; ++i) {
    int rb = m0 + wr + i * 16 + (khi << 2);
#pragma unroll
    for (int j = 0; j < JF; ++j) {
      int col = n0 + wc + j * 16 + r15;
      float bv = bias[col];
#pragma unroll
      for (int rr = 0; rr < 4; ++rr) {
        size_t idx = (size_t)(rb + rr) * N + col;
        float v = acc[i][j][rr] + bv;
        if constexpr (OM == 0) outb[idx] = f2bf(v);
        else outb[idx] = f2bf(bf2f(resid[idx]) + v);
      }
    }
  }
}

// ---------------------------------------------------------------------------
// Flash attention, swapped-operand 32x32 bf16 MFMA, LDS-staged K/V (dbuf),
// max-free softmax with C-prescaled Q (p = exp2(sacc) directly); softmax
// denominator l computed via ones-matrix MFMA on the matrix pipe (replaces
// the VALU sum tree). k-split x1, bh-affinity XCD remap.
// grid (16 qgroups, 32 bh) flat-remapped.
// ---------------------------------------------------------------------------
__global__ __launch_bounds__(256) void attn32(
    const u16* __restrict__ kvqp, u16* __restrict__ attno) {
  __shared__ u16 KV[2][4096];
  const int tid = threadIdx.x;
  const int lane = tid & 63;
  const int wv = tid >> 6;
  const int l31 = lane & 31;
  const int hi = lane >> 5;
  const int flat = blockIdx.y * 16 + blockIdx.x;
  const int qg = flat >> 5;
  const int bh = (flat & 7) | (((flat >> 3) & 3) << 3);
  const int b = bh >> 3, h = bh & 7;
  const int qt = qg * 4 + wv;
  const int q0 = qt << 5;

  v8s qf[4];
  {
    const u16* qb = kvqp + ((size_t)(bh * 64 + qt)) * 6144 + lane * 8;
#pragma unroll
    for (int ks = 0; ks < 4; ++ks) qf[ks] = *(const v8s*)(qb + (8 + ks) * 512);
  }
  v8s ones;
#pragma unroll
  for (int j = 0; j < 8; ++j) ones[j] = (short)0x3F80;  // bf16 1.0

  v16f o0 = {}, o1 = {}, lacc = {};

  const u16* tb = kvqp + ((size_t)(bh * 64)) * 6144;

  GLOAD_LDS(tb + tid * 8, &KV[0][tid * 8]);
  GLOAD_LDS(tb + 2048 + tid * 8, &KV[0][2048 + tid * 8]);
  __syncthreads();

  int cur = 0;
#pragma unroll 2
  for (int t = 0; t < 64; ++t) {
    if (t < 63) {
      const u16* nb = tb + (size_t)(t + 1) * 6144;
      GLOAD_LDS(nb + tid * 8, &KV[cur ^ 1][tid * 8]);
      GLOAD_LDS(nb + 2048 + tid * 8, &KV[cur ^ 1][2048 + tid * 8]);
    }
    v8s kf[4], vf[4];
#pragma unroll
    for (int ks = 0; ks < 4; ++ks) kf[ks] = *(const v8s*)(&KV[cur][ks * 512 + lane * 8]);
#pragma unroll
    for (int j = 0; j < 4; ++j) vf[j] = *(const v8s*)(&KV[cur][2048 + j * 512 + lane * 8]);

    __builtin_amdgcn_s_setprio(1);
    v16f sacc = {};
#pragma unroll
    for (int ks = 0; ks < 4; ++ks)
      sacc = __builtin_amdgcn_mfma_f32_32x32x16_bf16(kf[ks], qf[ks], sacc, 0, 0, 0);
    __builtin_amdgcn_s_setprio(0);

    // Q was pre-scaled by C: p = exp2(sacc) directly.
    float s[16];
#pragma unroll
    for (int r = 0; r < 16; ++r) s[r] = exp2f(sacc[r]);

    unsigned pk[8];
#pragma unroll
    for (int g = 0; g < 8; ++g) {
      unsigned u;
      asm("v_cvt_pk_bf16_f32 %0, %1, %2" : "=v"(u) : "v"(s[2 * g]), "v"(s[2 * g + 1]));
      pk[g] = u;
    }
    asm("v_permlane32_swap_b32 %0, %1" : "+v"(pk[2]), "+v"(pk[0]));
    asm("v_permlane32_swap_b32 %0, %1" : "+v"(pk[3]), "+v"(pk[1]));
    asm("v_permlane32_swap_b32 %0, %1" : "+v"(pk[6]), "+v"(pk[4]));
    asm("v_permlane32_swap_b32 %0, %1" : "+v"(pk[7]), "+v"(pk[5]));
    v4i w0, w1;
    w0[0] = pk[0]; w0[1] = pk[1]; w0[2] = pk[2]; w0[3] = pk[3];
    w1[0] = pk[4]; w1[1] = pk[5]; w1[2] = pk[6]; w1[3] = pk[7];
    v8s pf0 = *(v8s*)&w0;
    v8s pf1 = *(v8s*)&w1;

    __builtin_amdgcn_s_setprio(1);
    // l via ones-MFMA: lacc[r][q] = sum_k P[k][q] (every row identical).
    lacc = __builtin_amdgcn_mfma_f32_32x32x16_bf16(ones, pf0, lacc, 0, 0, 0);
    lacc = __builtin_amdgcn_mfma_f32_32x32x16_bf16(ones, pf1, lacc, 0, 0, 0);
    o0 = __builtin_amdgcn_mfma_f32_32x32x16_bf16(vf[0], pf0, o0, 0, 0, 0);
    o0 = __builtin_amdgcn_mfma_f32_32x32x16_bf16(vf[1], pf1, o0, 0, 0, 0);
    o1 = __builtin_amdgcn_mfma_f32_32x32x16_bf16(vf[2], pf0, o1, 0, 0, 0);
    o1 = __builtin_amdgcn_mfma_f32_32x32x16_bf16(vf[3], pf1, o1, 0, 0, 0);
    __builtin_amdgcn_s_setprio(0);

    __syncthreads();
    cur ^= 1;
  }

  float inv = 1.0f / lacc[0];
  u16* orow = attno + (size_t)(b * 2048 + q0 + l31) * 512 + h * 64;
#pragma unroll
  for (int dt = 0; dt < 2; ++dt) {
#pragma unroll
    for (int g = 0; g < 8; ++g) {
      int d = dt * 32 + ((2 * g) & 3) + 8 * (g >> 1) + 4 * hi;
      float a = (dt ? o1[2 * g] : o0[2 * g]) * inv;
      float bv = (dt ? o1[2 * g + 1] : o0[2 * g + 1]) * inv;
      unsigned u;
      asm("v_cvt_pk_bf16_f32 %0, %1, %2" : "=v"(u) : "v"(a), "v"(bv));
      *(unsigned*)(orow + d) = u;
    }
  }
}

// ---------------------------------------------------------------------------
// Fused GLU + depthwise conv(K=31) + BN + snake. In: g3 bf16 [8192,1024].
// Out: bf16 [8192,512]. Block: (chgroup 64, t-tile 128, batch).
// ---------------------------------------------------------------------------
__global__ __launch_bounds__(256) void dwconv_fused(
    const u16* __restrict__ g3, const float* __restrict__ dww,
    const float* __restrict__ dwb, const float* __restrict__ bng,
    const float* __restrict__ bnb, const float* __restrict__ bnm,
    const float* __restrict__ bnv, const float* __restrict__ la,
    const float* __restrict__ lb, u16* __restrict__ outp) {
  __shared__ float IN[160 * 64];
  __shared__ float WT[1984];
  __shared__ float PRM[4][64];
  const int tid = threadIdx.x;
  const int cg = blockIdx.x << 6;
  const int t0 = blockIdx.y << 7;
  const int bb = blockIdx.z;

  if (tid < 64) {
    int c = cg + tid;
    float sc = bng[c] / sqrtf(bnv[c] + 1e-5f);
    PRM[0][tid] = sc;
    PRM[1][tid] = (dwb[c] - bnm[c]) * sc + bnb[c];
    PRM[2][tid] = __expf(la[c]);
    PRM[3][tid] = 1.0f / (__expf(lb[c]) + 1e-9f);
  }
  for (int i = tid; i < 1984; i += 256) WT[i] = dww[cg * 31 + i];

#pragma unroll
  for (int p = 0; p < 5; ++p) {
    int r = p * 32 + (tid >> 3);
    int t = t0 - 16 + r;
    int c8 = (tid & 7) << 3;
    float4 lo = make_float4(0.f, 0.f, 0.f, 0.f);
    float4 hv = make_float4(0.f, 0.f, 0.f, 0.f);
    if (t >= 0 && t < 2048) {
      const u16* rp = g3 + ((size_t)(bb * 2048 + t)) * 1024 + cg + c8;
      v8s a8 = *(const v8s*)rp;
      v8s g8 = *(const v8s*)(rp + 512);
      float va[8];
#pragma unroll
      for (int j = 0; j < 8; ++j) {
        float fa = bf2f((u16)a8[j]);
        float fg = bf2f((u16)g8[j]);
        va[j] = fa / (1.f + __expf(-fg));
      }
      lo = make_float4(va[0], va[1], va[2], va[3]);
      hv = make_float4(va[4], va[5], va[6], va[7]);
    }
    *(float4*)&IN[r * 64 + c8] = lo;
    *(float4*)&IN[r * 64 + c8 + 4] = hv;
  }
  __syncthreads();

  const int ch = tid & 63;
  const int tg = tid >> 6;
  const float sc = PRM[0][ch], sh = PRM[1][ch], sa = PRM[2][ch], sib = PRM[3][ch];
  float w[31];
#pragma unroll
  for (int k = 0; k < 31; ++k) w[k] = WT[ch * 31 + k];

  for (int pass = 0; pass < 4; ++pass) {
    int tl = pass * 32 + tg * 8;
    float x[38];
#pragma unroll
    for (int i = 0; i < 38; ++i) x[i] = IN[(tl + 1 + i) * 64 + ch];
    float acc[8] = {0.f, 0.f, 0.f, 0.f, 0.f, 0.f, 0.f, 0.f};
#pragma unroll
    for (int k = 0; k < 31; ++k)
#pragma unroll
      for (int j = 0; j < 8; ++j) acc[j] = fmaf(x[k + j], w[k], acc[j]);
#pragma unroll
    for (int j = 0; j < 8; ++j) {
      float v = acc[j] * sc + sh;
      float s = __sinf(sa * v);
      v += s * s * sib;
      outp[((size_t)(bb * 2048 + t0 + tl + j)) * 512 + cg + ch] = f2bf(v);
    }
  }
}

// ---------------------------------------------------------------------------
extern "C" void kernel_launch(void* const* d_in, const int* in_sizes, int n_in,
                              void* d_out, int out_size, void* d_ws, size_t ws_size,
                              hipStream_t stream) {
  const float* x_in = (const float*)d_in[0];
  const float* ff1_norm_w = (const float*)d_in[1];
  const float* ff1_w1 = (const float*)d_in[2];
  const float* ff1_a = (const float*)d_in[3];
  const float* ff1_b = (const float*)d_in[4];
  const float* ff1_w2 = (const float*)d_in[5];
  const float* attn_norm_w = (const float*)d_in[6];
  const float* in_proj_w = (const float*)d_in[7];
  const float* in_proj_b = (const float*)d_in[8];
  const float* out_proj_w = (const float*)d_in[9];
  const float* out_proj_b = (const float*)d_in[10];
  const float* conv_norm_w = (const float*)d_in[11];
  const float* pw1_w = (const float*)d_in[12];
  const float* dw_w = (const float*)d_in[13];
  const float* dw_b = (const float*)d_in[14];
  const float* bn_g = (const float*)d_in[15];
  const float* bn_b = (const float*)d_in[16];
  const float* bn_m = (const float*)d_in[17];
  const float* bn_v = (const float*)d_in[18];
  const float* snake_a = (const float*)d_in[19];
  const float* snake_b = (const float*)d_in[20];
  const float* pw2_w = (const float*)d_in[21];
  const float* ff2_norm_w = (const float*)d_in[22];
  const float* ff2_w1 = (const float*)d_in[23];
  const float* ff2_a = (const float*)d_in[24];
  const float* ff2_b = (const float*)d_in[25];
  const float* ff2_w2 = (const float*)d_in[26];
  const float* final_norm_w = (const float*)d_in[27];
  float* out = (float*)d_out;

  char* ws = (char*)d_ws;
  u16* x_bf = (u16*)(ws + 0);                          // 8 MiB  (bf16 of x_in)
  u16* x_cur = (u16*)(ws + 8388608);                   // 8 MiB  (bf16 residual)
  // attn phase:
  u16* kvqp = (u16*)(ws + 41943040);                   // 24 MiB (packed Q/K/V)
  u16* attno = (u16*)(ws + 100663296);                 // 8 MiB
  // FFN phase:
  u16* h_b = (u16*)(ws + 16777216);                    // 32 MiB
  // conv phase:
  u16* g3b = (u16*)(ws + 16777216);                    // 16 MiB
  u16* convout = (u16*)(ws + 50331648);                // 8 MiB
  signed char* a8a = (signed char*)(ws + 83886080);    // 4 MiB
  signed char* a8b = (signed char*)(ws + 88080384);    // 16 MiB
  signed char* wq = (signed char*)(ws + 113246208);    // ternary 4.75 MiB + in_proj i8
  signed char* wq_w1 = wq;
  signed char* wq_w2 = wq + 1048576;
  signed char* wq_p1 = wq + 2097152;
  signed char* wq_p2 = wq + 2621440;
  signed char* wq_f21 = wq + 2883584;
  signed char* wq_f22 = wq + 3932160;
  signed char* wq_ip = wq + 4980736;                   // 786432 B (int8 in_proj)
  u16* wb = (u16*)(ws + 119013376);                    // 512 KiB (bf16 out_proj)
  u16* wb_op = wb;
  float* scales = (float*)(ws + 120324096);            // 7 floats
  float* partials = (float*)(ws + 120324352);          // 7*64 floats
  float* ascale = (float*)(ws + 120325888);            // 32 KiB
  float* tabs = (float*)(ws + 120358912);              // 32 KiB

  // --- weight prep ---
  wabs_stage1<<<448, 256, 0, stream>>>(ff1_w1, ff1_w2, pw1_w, pw2_w, ff2_w1, ff2_w2,
                                       in_proj_w, partials);
  wquant_all<<<dim3(128, 7), 256, 0, stream>>>(ff1_w1, ff1_w2, pw1_w, pw2_w, ff2_w1, ff2_w2,
                                               in_proj_w, partials, scales, wq);
  wcvt_tabs<<<264, 256, 0, stream>>>(out_proj_w, wb, ff1_a, ff1_b, ff2_a, ff2_b, tabs);

  // --- FFN1: x_cur = x + 0.5*ffn(x)  (snake fused into up-GEMM epilogue) ---
  rmsnorm_f32x<<<2048, 256, 0, stream>>>(x_in, ff1_norm_w, a8a, x_bf, ascale);
  gemm_i8_t<128, 128, 2><<<dim3(16, 64), 256, 0, stream>>>(
      a8a, wq_w1, scales + 0, ascale, nullptr, 1.0f, h_b, 2048, 512, tabs, tabs + 2048, nullptr);
  rq2048_wave<<<2048, 256, 0, stream>>>(h_b, a8b, ascale);
  gemm_i8_t<64, 64, 1><<<dim3(8, 128), 256, 0, stream>>>(
      a8b, wq_w2, scales + 1, ascale, x_bf, 0.5f, x_cur, 512, 2048, nullptr, nullptr, nullptr);

  // --- MHA: x_cur += mha(x_cur)  (int8 in_proj scatters packed kvqp) ---
  rmsnorm_wave<<<2048, 256, 0, stream>>>(x_cur, attn_norm_w, 1, nullptr, a8a, nullptr, ascale);
  gemm_i8_t<128, 128, 3><<<dim3(12, 64), 256, 0, stream>>>(
      a8a, wq_ip, scales + 6, ascale, nullptr, 1.0f, kvqp, 1536, 512, nullptr, nullptr,
      in_proj_b);
  attn32<<<dim3(16, 32), 256, 0, stream>>>(kvqp, attno);
  gemm_bf16_t<64, 1><<<dim3(8, 64), 256, 0, stream>>>(
      attno, wb_op, out_proj_b, x_cur, x_cur, 512, 512);

  // --- conv branch: x_cur += conv(x_cur) ---
  rmsnorm_wave<<<2048, 256, 0, stream>>>(x_cur, conv_norm_w, 1, nullptr, a8a, nullptr, ascale);
  gemm_i8_t<128, 128, 0><<<dim3(8, 64), 256, 0, stream>>>(
      a8a, wq_p1, scales + 2, ascale, nullptr, 1.0f, g3b, 1024, 512, nullptr, nullptr, nullptr);
  dwconv_fused<<<dim3(8, 16, 4), 256, 0, stream>>>(g3b, dw_w, dw_b, bn_g, bn_b, bn_m, bn_v,
                                                   snake_a, snake_b, convout);
  rowquant_wave<<<2048, 256, 0, stream>>>(convout, a8a, ascale);
  gemm_i8_t<64, 64, 1><<<dim3(8, 128), 256, 0, stream>>>(
      a8a, wq_p2, scales + 3, ascale, x_cur, 1.0f, x_cur, 512, 512, nullptr, nullptr, nullptr);

  // --- FFN2: x_cur += 0.5*ffn(x_cur) ---
  rmsnorm_wave<<<2048, 256, 0, stream>>>(x_cur, ff2_norm_w, 1, nullptr, a8a, nullptr, ascale);
  gemm_i8_t<128, 128, 2><<<dim3(16, 64), 256, 0, stream>>>(
      a8a, wq_f21, scales + 4, ascale, nullptr, 1.0f, h_b, 2048, 512, tabs + 4096, tabs + 6144,
      nullptr);
  rq2048_wave<<<2048, 256, 0, stream>>>(h_b, a8b, ascale);
  gemm_i8_t<64, 64, 1><<<dim3(8, 128), 256, 0, stream>>>(
      a8b, wq_f22, scales + 5, ascale, x_cur, 0.5f, x_cur, 512, 2048, nullptr, nullptr, nullptr);

  // --- final rmsnorm -> out (f32) ---
  rmsnorm_wave<<<2048, 256, 0, stream>>>(x_cur, final_norm_w, 0, out, nullptr, nullptr, nullptr);
}